// Round 1
// baseline (602.169 us; speedup 1.0000x reference)
//
#include <hip/hip_runtime.h>
#include <math.h>

// ---------------- degree / normalization ----------------

__global__ __launch_bounds__(256) void count_deg_kernel(const int* __restrict__ dst, int E,
                                                        int* __restrict__ deg) {
    int e = blockIdx.x * 256 + threadIdx.x;
    if (e < E) atomicAdd(&deg[dst[e]], 1);
}

__global__ __launch_bounds__(256) void dinv_kernel(const int* __restrict__ deg,
                                                   float* __restrict__ dinv, int n) {
    int i = blockIdx.x * 256 + threadIdx.x;
    if (i < n) dinv[i] = rsqrtf((float)(deg[i] + 1));  // +1 self loop
}

// exclusive scan of deg[0..n) -> rowptr[0..n], single block of 1024
__global__ __launch_bounds__(1024) void scan_kernel(const int* __restrict__ deg,
                                                    int* __restrict__ rowptr, int n) {
    __shared__ int sm[1024];
    int t = threadIdx.x;
    int ch = (n + 1023) >> 10;
    int start = t * ch;
    int end = min(start + ch, n);
    int s = 0;
    for (int i = start; i < end; ++i) s += deg[i];
    sm[t] = s;
    __syncthreads();
    for (int off = 1; off < 1024; off <<= 1) {
        int v = (t >= off) ? sm[t - off] : 0;
        __syncthreads();
        sm[t] += v;
        __syncthreads();
    }
    int run = (t > 0) ? sm[t - 1] : 0;
    for (int i = start; i < end; ++i) { rowptr[i] = run; run += deg[i]; }
    if (t == 1023) rowptr[n] = sm[1023];
}

__global__ __launch_bounds__(256) void scatter_kernel(const int* __restrict__ src,
                                                      const int* __restrict__ dst, int E,
                                                      const int* __restrict__ rowptr,
                                                      int* __restrict__ cursor,
                                                      int* __restrict__ csrsrc) {
    int e = blockIdx.x * 256 + threadIdx.x;
    if (e < E) {
        int d = dst[e];
        int pos = atomicAdd(&cursor[d], 1);
        csrsrc[rowptr[d] + pos] = src[e];
    }
}

// ---------------- aggregation: out[i] = dinv[i]*(sum_e dinv[s]*X[s] + dinv[i]*X[i]) ----------------
// one wave (64 lanes) per node, float2 per lane (128 dims)

__global__ __launch_bounds__(256) void aggregate_kernel(const float* __restrict__ X,
                                                        const float* __restrict__ dinv,
                                                        const int* __restrict__ rowptr,
                                                        const int* __restrict__ csrsrc,
                                                        float* __restrict__ out, int n) {
    int node = blockIdx.x * 4 + (threadIdx.x >> 6);
    int lane = threadIdx.x & 63;
    if (node >= n) return;
    float di = dinv[node];
    float2 acc = *(const float2*)(X + (size_t)node * 128 + (lane << 1));
    acc.x *= di;
    acc.y *= di;
    int e0 = rowptr[node], e1 = rowptr[node + 1];
    for (int e = e0; e < e1; ++e) {
        int s = csrsrc[e];
        float ds = dinv[s];
        float2 v = *(const float2*)(X + (size_t)s * 128 + (lane << 1));
        acc.x += ds * v.x;
        acc.y += ds * v.y;
    }
    acc.x *= di;
    acc.y *= di;
    *(float2*)(out + (size_t)node * 128 + (lane << 1)) = acc;
}

// ---------------- fp32 GEMM + bias + relu: C[M x N] = relu(A[M x 128] @ W[128 x N] + b) ----------------
// block: 256 threads, 64 rows; cols in chunks of 64; thread tile 4x4.
// As XOR-swizzled (k ^ 8*((r>>2)&3)) so the 4 per-thread row reads hit 4 distinct banks.

template <int N>
__global__ __launch_bounds__(256) void gemm_bias_relu(const float* __restrict__ A,
                                                      const float* __restrict__ W,
                                                      const float* __restrict__ bias,
                                                      float* __restrict__ C, int M) {
    __shared__ float As[64 * 128];   // 32 KB
    __shared__ float Ws[128 * 64];   // 32 KB
    int t = threadIdx.x;
    int row0 = blockIdx.x * 64;

#pragma unroll
    for (int i = 0; i < 8; ++i) {
        int f = t + i * 256;          // float4 index in 64x128 tile
        int r = f >> 5;               // row
        int k = (f & 31) << 2;        // col (multiple of 4)
        float4 v = make_float4(0.f, 0.f, 0.f, 0.f);
        int gr = row0 + r;
        if (gr < M) v = *(const float4*)(A + (size_t)gr * 128 + k);
        int sws = ((r >> 2) & 3) * 8;
        *(float4*)(As + r * 128 + (k ^ sws)) = v;
    }

    int tx = t & 15;        // col group: 4 cols
    int ty = t >> 4;        // row group: 4 rows (16 groups -> 64 rows)
    int sw = (ty & 3) * 8;  // read-side swizzle, matches store

    for (int cc = 0; cc < N; cc += 64) {
        __syncthreads();
#pragma unroll
        for (int i = 0; i < 8; ++i) {
            int f = t + i * 256;      // float4 index in 128x64 chunk
            int k = f >> 4;
            int c = (f & 15) << 2;
            *(float4*)(Ws + k * 64 + c) = *(const float4*)(W + (size_t)k * N + cc + c);
        }
        __syncthreads();

        float acc[4][4];
#pragma unroll
        for (int i = 0; i < 4; ++i)
#pragma unroll
            for (int j = 0; j < 4; ++j) acc[i][j] = 0.f;

#pragma unroll 4
        for (int k = 0; k < 128; ++k) {
            float4 w = *(const float4*)(Ws + k * 64 + (tx << 2));
            int ks = k ^ sw;
            float a0 = As[(ty * 4 + 0) * 128 + ks];
            float a1 = As[(ty * 4 + 1) * 128 + ks];
            float a2 = As[(ty * 4 + 2) * 128 + ks];
            float a3 = As[(ty * 4 + 3) * 128 + ks];
            acc[0][0] += a0 * w.x; acc[0][1] += a0 * w.y; acc[0][2] += a0 * w.z; acc[0][3] += a0 * w.w;
            acc[1][0] += a1 * w.x; acc[1][1] += a1 * w.y; acc[1][2] += a1 * w.z; acc[1][3] += a1 * w.w;
            acc[2][0] += a2 * w.x; acc[2][1] += a2 * w.y; acc[2][2] += a2 * w.z; acc[2][3] += a2 * w.w;
            acc[3][0] += a3 * w.x; acc[3][1] += a3 * w.y; acc[3][2] += a3 * w.z; acc[3][3] += a3 * w.w;
        }

#pragma unroll
        for (int i = 0; i < 4; ++i) {
            int gr = row0 + ty * 4 + i;
            if (gr < M) {
                int gc = cc + (tx << 2);
                float4 o;
                o.x = fmaxf(acc[i][0] + bias[gc + 0], 0.f);
                o.y = fmaxf(acc[i][1] + bias[gc + 1], 0.f);
                o.z = fmaxf(acc[i][2] + bias[gc + 2], 0.f);
                o.w = fmaxf(acc[i][3] + bias[gc + 3], 0.f);
                *(float4*)(C + (size_t)gr * N + gc) = o;
            }
        }
    }
}

// ---------------- attention pooling ----------------

__global__ __launch_bounds__(256) void logits_kernel(const float* __restrict__ emb,
                                                     const float* __restrict__ Wa,
                                                     const float* __restrict__ ba,
                                                     float* __restrict__ logits, int n) {
    int node = blockIdx.x * 4 + (threadIdx.x >> 6);
    int lane = threadIdx.x & 63;
    if (node >= n) return;
    float4 v = *(const float4*)(emb + (size_t)node * 256 + (lane << 2));
    float4 w = *(const float4*)(Wa + (lane << 2));
    float s = v.x * w.x + v.y * w.y + v.z * w.z + v.w * w.w;
    for (int off = 32; off > 0; off >>= 1) s += __shfl_down(s, off);
    if (lane == 0) logits[node] = s + ba[0];
}

__global__ __launch_bounds__(256) void reduce_max_kernel(const float* __restrict__ logits, int n,
                                                         float* __restrict__ part) {
    __shared__ float sm[256];
    float m = -INFINITY;
    for (int i = blockIdx.x * 256 + threadIdx.x; i < n; i += gridDim.x * 256)
        m = fmaxf(m, logits[i]);
    sm[threadIdx.x] = m;
    __syncthreads();
    for (int off = 128; off > 0; off >>= 1) {
        if (threadIdx.x < off) sm[threadIdx.x] = fmaxf(sm[threadIdx.x], sm[threadIdx.x + off]);
        __syncthreads();
    }
    if (threadIdx.x == 0) part[blockIdx.x] = sm[0];
}

__global__ __launch_bounds__(256) void final_max_kernel(const float* __restrict__ part, int np,
                                                        float* __restrict__ gmax) {
    __shared__ float sm[256];
    sm[threadIdx.x] = (threadIdx.x < np) ? part[threadIdx.x] : -INFINITY;
    __syncthreads();
    for (int off = 128; off > 0; off >>= 1) {
        if (threadIdx.x < off) sm[threadIdx.x] = fmaxf(sm[threadIdx.x], sm[threadIdx.x + off]);
        __syncthreads();
    }
    if (threadIdx.x == 0) gmax[0] = sm[0];
}

__global__ __launch_bounds__(256) void sumexp_kernel(const float* __restrict__ logits, int n,
                                                     const float* __restrict__ gmax,
                                                     float* __restrict__ part) {
    __shared__ float sm[256];
    float g = gmax[0];
    float s = 0.f;
    for (int i = blockIdx.x * 256 + threadIdx.x; i < n; i += gridDim.x * 256)
        s += expf(logits[i] - g);
    sm[threadIdx.x] = s;
    __syncthreads();
    for (int off = 128; off > 0; off >>= 1) {
        if (threadIdx.x < off) sm[threadIdx.x] += sm[threadIdx.x + off];
        __syncthreads();
    }
    if (threadIdx.x == 0) part[blockIdx.x] = sm[0];
}

// out_tail[c] (pre-zeroed) += sum_i exp(l_i - gmax) * emb[i][c]
__global__ __launch_bounds__(256) void weighted_sum_kernel(const float* __restrict__ emb,
                                                           const float* __restrict__ logits,
                                                           const float* __restrict__ gmax,
                                                           float* __restrict__ out, int n) {
    float g = gmax[0];
    int c = threadIdx.x;
    float acc = 0.f;
    for (int i = blockIdx.x; i < n; i += gridDim.x) {
        float w = expf(logits[i] - g);
        acc += w * emb[(size_t)i * 256 + c];
    }
    atomicAdd(&out[c], acc);
}

__global__ __launch_bounds__(256) void normalize_kernel(float* __restrict__ out,
                                                        const float* __restrict__ part, int np) {
    __shared__ float sm[256];
    sm[threadIdx.x] = (threadIdx.x < np) ? part[threadIdx.x] : 0.f;
    __syncthreads();
    for (int off = 128; off > 0; off >>= 1) {
        if (threadIdx.x < off) sm[threadIdx.x] += sm[threadIdx.x + off];
        __syncthreads();
    }
    out[threadIdx.x] = out[threadIdx.x] / sm[0];
}

// ---------------- launch ----------------

extern "C" void kernel_launch(void* const* d_in, const int* in_sizes, int n_in,
                              void* d_out, int out_size, void* d_ws, size_t ws_size,
                              hipStream_t stream) {
    const float* x  = (const float*)d_in[0];
    const int* ei   = (const int*)d_in[1];
    const float* W1 = (const float*)d_in[2];
    const float* b1 = (const float*)d_in[3];
    const float* W2 = (const float*)d_in[4];
    const float* b2 = (const float*)d_in[5];
    const float* Wa = (const float*)d_in[6];
    const float* ba = (const float*)d_in[7];
    float* out = (float*)d_out;

    const int n = in_sizes[0] / 128;  // 50000
    const int E = in_sizes[1] / 2;    // 800000
    const int* srcA = ei;
    const int* dstA = ei + E;

    // workspace layout (all 4-byte units)
    float* ws     = (float*)d_ws;
    float* agg    = ws;                         // n*128
    float* h1     = agg + (size_t)n * 128;      // n*128
    float* dinv   = h1 + (size_t)n * 128;       // n
    float* logits = dinv + n;                   // n
    float* partA  = logits + n;                 // 128
    float* partB  = partA + 128;                // 128
    float* gmax   = partB + 128;                // 1
    int* deg      = (int*)(gmax + 1);           // n
    int* rowptr   = deg + n;                    // n+1
    int* cursor   = rowptr + n + 1;             // n
    int* csrsrc   = cursor + n;                 // E

    // zero deg + rowptr + cursor (contiguous, 3n+1 ints) and the graph-embedding tail
    hipMemsetAsync(deg, 0, sizeof(int) * (size_t)(3 * n + 1), stream);
    hipMemsetAsync(out + (size_t)n * 256, 0, sizeof(float) * 256, stream);

    count_deg_kernel<<<(E + 255) / 256, 256, 0, stream>>>(dstA, E, deg);
    dinv_kernel<<<(n + 255) / 256, 256, 0, stream>>>(deg, dinv, n);
    scan_kernel<<<1, 1024, 0, stream>>>(deg, rowptr, n);
    scatter_kernel<<<(E + 255) / 256, 256, 0, stream>>>(srcA, dstA, E, rowptr, cursor, csrsrc);

    int aggBlocks = (n + 3) / 4;
    int gemmBlocks = (n + 63) / 64;

    aggregate_kernel<<<aggBlocks, 256, 0, stream>>>(x, dinv, rowptr, csrsrc, agg, n);
    gemm_bias_relu<128><<<gemmBlocks, 256, 0, stream>>>(agg, W1, b1, h1, n);
    aggregate_kernel<<<aggBlocks, 256, 0, stream>>>(h1, dinv, rowptr, csrsrc, agg, n);
    gemm_bias_relu<256><<<gemmBlocks, 256, 0, stream>>>(agg, W2, b2, out, n);

    logits_kernel<<<(n + 3) / 4, 256, 0, stream>>>(out, Wa, ba, logits, n);
    reduce_max_kernel<<<128, 256, 0, stream>>>(logits, n, partA);
    final_max_kernel<<<1, 256, 0, stream>>>(partA, 128, gmax);
    sumexp_kernel<<<128, 256, 0, stream>>>(logits, n, gmax, partB);
    weighted_sum_kernel<<<512, 256, 0, stream>>>(out, logits, gmax, out + (size_t)n * 256, n);
    normalize_kernel<<<1, 256, 0, stream>>>(out + (size_t)n * 256, partB, 128);
}

// Round 2
// 544.788 us; speedup vs baseline: 1.1053x; 1.1053x over previous
//
#include <hip/hip_runtime.h>
#include <math.h>

// ---------------- CSR build ----------------

__global__ __launch_bounds__(256) void count_deg_kernel(const int* __restrict__ dst, int E,
                                                        int* __restrict__ deg) {
    int e = blockIdx.x * 256 + threadIdx.x;
    if (e < E) atomicAdd(&deg[dst[e]], 1);
}

// exclusive scan of deg[0..n) -> rowptr[0..n], single block of 1024
__global__ __launch_bounds__(1024) void scan_kernel(const int* __restrict__ deg,
                                                    int* __restrict__ rowptr, int n) {
    __shared__ int sm[1024];
    int t = threadIdx.x;
    int ch = (n + 1023) >> 10;
    int start = t * ch;
    int end = min(start + ch, n);
    int s = 0;
    for (int i = start; i < end; ++i) s += deg[i];
    sm[t] = s;
    __syncthreads();
    for (int off = 1; off < 1024; off <<= 1) {
        int v = (t >= off) ? sm[t - off] : 0;
        __syncthreads();
        sm[t] += v;
        __syncthreads();
    }
    int run = (t > 0) ? sm[t - 1] : 0;
    for (int i = start; i < end; ++i) { rowptr[i] = run; run += deg[i]; }
    if (t == 1023) rowptr[n] = sm[1023];
}

__global__ __launch_bounds__(256) void scatter_kernel(const int* __restrict__ src,
                                                      const int* __restrict__ dst, int E,
                                                      const int* __restrict__ rowptr,
                                                      int* __restrict__ cursor,
                                                      int* __restrict__ csrsrc) {
    int e = blockIdx.x * 256 + threadIdx.x;
    if (e < E) {
        int d = dst[e];
        int pos = atomicAdd(&cursor[d], 1);
        csrsrc[rowptr[d] + pos] = src[e];
    }
}

// ---------------- dinv + prescale: xs[i] = dinv[i]*x[i], dinv[i]=rsqrt(deg+1) ----------------

__global__ __launch_bounds__(256) void dinv_prescale_kernel(const float* __restrict__ x,
                                                            const int* __restrict__ deg,
                                                            float* __restrict__ dinv,
                                                            float* __restrict__ xs, int n) {
    int node = blockIdx.x * 4 + (threadIdx.x >> 6);
    int lane = threadIdx.x & 63;
    if (node >= n) return;
    float di = rsqrtf((float)(deg[node] + 1));
    if (lane == 0) dinv[node] = di;
    float2 v = *(const float2*)(x + (size_t)node * 128 + (lane << 1));
    *(float2*)(xs + (size_t)node * 128 + (lane << 1)) = make_float2(di * v.x, di * v.y);
}

// ---------------- aggregation on PRESCALED features ----------------
// out[i] = dinv[i] * ( xs[i] + sum_e xs[src_e] )      (xs already carries dinv[src])
// one 32-lane group per node, float4 per lane, edge loop unrolled x4 for MLP.

__global__ __launch_bounds__(256) void aggregate_kernel(const float* __restrict__ Xs,
                                                        const float* __restrict__ dinv,
                                                        const int* __restrict__ rowptr,
                                                        const int* __restrict__ deg,
                                                        const int* __restrict__ csrsrc,
                                                        float* __restrict__ out, int n) {
    int node = blockIdx.x * 8 + (threadIdx.x >> 5);
    int sl = threadIdx.x & 31;
    if (node >= n) return;
    const float4* Xv = (const float4*)Xs;
    float4 acc = Xv[(size_t)node * 32 + sl];  // self term (prescaled)
    int e0 = rowptr[node];
    int e1 = e0 + deg[node];
    int e = e0;
    for (; e + 4 <= e1; e += 4) {
        int s0 = csrsrc[e], s1 = csrsrc[e + 1], s2 = csrsrc[e + 2], s3 = csrsrc[e + 3];
        float4 v0 = Xv[(size_t)s0 * 32 + sl];
        float4 v1 = Xv[(size_t)s1 * 32 + sl];
        float4 v2 = Xv[(size_t)s2 * 32 + sl];
        float4 v3 = Xv[(size_t)s3 * 32 + sl];
        acc.x += (v0.x + v1.x) + (v2.x + v3.x);
        acc.y += (v0.y + v1.y) + (v2.y + v3.y);
        acc.z += (v0.z + v1.z) + (v2.z + v3.z);
        acc.w += (v0.w + v1.w) + (v2.w + v3.w);
    }
    for (; e < e1; ++e) {
        int s = csrsrc[e];
        float4 v = Xv[(size_t)s * 32 + sl];
        acc.x += v.x; acc.y += v.y; acc.z += v.z; acc.w += v.w;
    }
    float di = dinv[node];
    ((float4*)out)[(size_t)node * 32 + sl] = make_float4(di * acc.x, di * acc.y, di * acc.z, di * acc.w);
}

// ---------------- fp32 GEMM + bias + relu (+ optional dinv scale, + optional fused logits) ----------
// C[M x N] = relu(A[M x 128] @ W[128 x N] + b) [* dinv[row]]
// block: 256 threads, 64 rows; cols in chunks of 64; thread tile 4x4.

template <int N, bool SCALE_DINV, bool DO_LOGITS>
__global__ __launch_bounds__(256) void gemm_bias_relu(const float* __restrict__ A,
                                                      const float* __restrict__ W,
                                                      const float* __restrict__ bias,
                                                      float* __restrict__ C, int M,
                                                      const float* __restrict__ dinv,
                                                      const float* __restrict__ Wa,
                                                      const float* __restrict__ ba,
                                                      float* __restrict__ logits) {
    __shared__ float As[64 * 128];   // 32 KB
    __shared__ float Ws[128 * 64];   // 32 KB
    __shared__ float red[64 * 17];   // logits reduction (4.4 KB)
    int t = threadIdx.x;
    int row0 = blockIdx.x * 64;

#pragma unroll
    for (int i = 0; i < 8; ++i) {
        int f = t + i * 256;          // float4 index in 64x128 tile
        int r = f >> 5;               // row
        int k = (f & 31) << 2;        // col (multiple of 4)
        float4 v = make_float4(0.f, 0.f, 0.f, 0.f);
        int gr = row0 + r;
        if (gr < M) v = *(const float4*)(A + (size_t)gr * 128 + k);
        int sws = ((r >> 2) & 3) * 8;
        *(float4*)(As + r * 128 + (k ^ sws)) = v;
    }

    int tx = t & 15;        // col group: 4 cols
    int ty = t >> 4;        // row group: 4 rows (16 groups -> 64 rows)
    int sw = (ty & 3) * 8;  // read-side swizzle, matches store

    float lsum[4] = {0.f, 0.f, 0.f, 0.f};
    float dsc[4];
    if (SCALE_DINV) {
#pragma unroll
        for (int i = 0; i < 4; ++i) {
            int gr = row0 + ty * 4 + i;
            dsc[i] = (gr < M) ? dinv[gr] : 0.f;
        }
    }

    for (int cc = 0; cc < N; cc += 64) {
        __syncthreads();
#pragma unroll
        for (int i = 0; i < 8; ++i) {
            int f = t + i * 256;      // float4 index in 128x64 chunk
            int k = f >> 4;
            int c = (f & 15) << 2;
            *(float4*)(Ws + k * 64 + c) = *(const float4*)(W + (size_t)k * N + cc + c);
        }
        __syncthreads();

        float acc[4][4];
#pragma unroll
        for (int i = 0; i < 4; ++i)
#pragma unroll
            for (int j = 0; j < 4; ++j) acc[i][j] = 0.f;

#pragma unroll 4
        for (int k = 0; k < 128; ++k) {
            float4 w = *(const float4*)(Ws + k * 64 + (tx << 2));
            int ks = k ^ sw;
            float a0 = As[(ty * 4 + 0) * 128 + ks];
            float a1 = As[(ty * 4 + 1) * 128 + ks];
            float a2 = As[(ty * 4 + 2) * 128 + ks];
            float a3 = As[(ty * 4 + 3) * 128 + ks];
            acc[0][0] += a0 * w.x; acc[0][1] += a0 * w.y; acc[0][2] += a0 * w.z; acc[0][3] += a0 * w.w;
            acc[1][0] += a1 * w.x; acc[1][1] += a1 * w.y; acc[1][2] += a1 * w.z; acc[1][3] += a1 * w.w;
            acc[2][0] += a2 * w.x; acc[2][1] += a2 * w.y; acc[2][2] += a2 * w.z; acc[2][3] += a2 * w.w;
            acc[3][0] += a3 * w.x; acc[3][1] += a3 * w.y; acc[3][2] += a3 * w.z; acc[3][3] += a3 * w.w;
        }

        int gc = cc + (tx << 2);
        float4 wa4;
        if (DO_LOGITS) wa4 = *(const float4*)(Wa + gc);
#pragma unroll
        for (int i = 0; i < 4; ++i) {
            int gr = row0 + ty * 4 + i;
            float4 o;
            o.x = fmaxf(acc[i][0] + bias[gc + 0], 0.f);
            o.y = fmaxf(acc[i][1] + bias[gc + 1], 0.f);
            o.z = fmaxf(acc[i][2] + bias[gc + 2], 0.f);
            o.w = fmaxf(acc[i][3] + bias[gc + 3], 0.f);
            if (SCALE_DINV) { o.x *= dsc[i]; o.y *= dsc[i]; o.z *= dsc[i]; o.w *= dsc[i]; }
            if (DO_LOGITS) lsum[i] += o.x * wa4.x + o.y * wa4.y + o.z * wa4.z + o.w * wa4.w;
            if (gr < M) *(float4*)(C + (size_t)gr * N + gc) = o;
        }
    }

    if (DO_LOGITS) {
        __syncthreads();
#pragma unroll
        for (int i = 0; i < 4; ++i) red[(ty * 4 + i) * 17 + tx] = lsum[i];
        __syncthreads();
        if (t < 64) {
            int gr = row0 + t;
            if (gr < M) {
                float s = ba[0];
#pragma unroll
                for (int xq = 0; xq < 16; ++xq) s += red[t * 17 + xq];
                logits[gr] = s;
            }
        }
    }
}

// ---------------- attention pooling ----------------
// pass 1: per-block online (max, sumexp)
__global__ __launch_bounds__(256) void maxsum_kernel(const float* __restrict__ logits, int n,
                                                     float2* __restrict__ part) {
    float m = -INFINITY, s = 0.f;
    for (int i = blockIdx.x * 256 + threadIdx.x; i < n; i += gridDim.x * 256) {
        float v = logits[i];
        if (v > m) { s = s * expf(m - v) + 1.f; m = v; }
        else s += expf(v - m);
    }
    __shared__ float sm[256], ss[256];
    sm[threadIdx.x] = m; ss[threadIdx.x] = s;
    __syncthreads();
    for (int off = 128; off > 0; off >>= 1) {
        if (threadIdx.x < off) {
            float m1 = sm[threadIdx.x], s1 = ss[threadIdx.x];
            float m2 = sm[threadIdx.x + off], s2 = ss[threadIdx.x + off];
            float M = fmaxf(m1, m2);
            sm[threadIdx.x] = M;
            ss[threadIdx.x] = s1 * expf(m1 - M) + s2 * expf(m2 - M);
        }
        __syncthreads();
    }
    if (threadIdx.x == 0) part[blockIdx.x] = make_float2(sm[0], ss[0]);
}

// pass 2: merge 64 pairs -> gms = {gmax, gsum}
__global__ __launch_bounds__(64) void merge_kernel(const float2* __restrict__ part,
                                                   float* __restrict__ gms) {
    __shared__ float sm[64], ss[64];
    float2 p = part[threadIdx.x];
    sm[threadIdx.x] = p.x; ss[threadIdx.x] = p.y;
    __syncthreads();
    for (int off = 32; off > 0; off >>= 1) {
        if (threadIdx.x < off) {
            float m1 = sm[threadIdx.x], s1 = ss[threadIdx.x];
            float m2 = sm[threadIdx.x + off], s2 = ss[threadIdx.x + off];
            float M = fmaxf(m1, m2);
            sm[threadIdx.x] = M;
            ss[threadIdx.x] = s1 * expf(m1 - M) + s2 * expf(m2 - M);
        }
        __syncthreads();
    }
    if (threadIdx.x == 0) { gms[0] = sm[0]; gms[1] = ss[0]; }
}

// outTail[c] (pre-zeroed) += sum_i exp(l_i - gmax) * emb[i][c]
__global__ __launch_bounds__(256) void weighted_sum_kernel(const float* __restrict__ emb,
                                                           const float* __restrict__ logits,
                                                           const float* __restrict__ gms,
                                                           float* __restrict__ outTail, int n) {
    float g = gms[0];
    int c = threadIdx.x;
    float acc = 0.f;
    for (int i = blockIdx.x; i < n; i += gridDim.x) {
        float w = expf(logits[i] - g);
        acc += w * emb[(size_t)i * 256 + c];
    }
    atomicAdd(&outTail[c], acc);
}

__global__ __launch_bounds__(256) void normalize_kernel(float* __restrict__ outTail,
                                                        const float* __restrict__ gms) {
    outTail[threadIdx.x] = outTail[threadIdx.x] / gms[1];
}

// ---------------- launch ----------------

extern "C" void kernel_launch(void* const* d_in, const int* in_sizes, int n_in,
                              void* d_out, int out_size, void* d_ws, size_t ws_size,
                              hipStream_t stream) {
    const float* x  = (const float*)d_in[0];
    const int* ei   = (const int*)d_in[1];
    const float* W1 = (const float*)d_in[2];
    const float* b1 = (const float*)d_in[3];
    const float* W2 = (const float*)d_in[4];
    const float* b2 = (const float*)d_in[5];
    const float* Wa = (const float*)d_in[6];
    const float* ba = (const float*)d_in[7];
    float* out = (float*)d_out;

    const int n = in_sizes[0] / 128;  // 50000
    const int E = in_sizes[1] / 2;    // 800000
    const int* srcA = ei;
    const int* dstA = ei + E;

    // workspace layout (4-byte units)
    float* ws     = (float*)d_ws;
    float* xs     = ws;                         // n*128  (prescaled x; reused as h1s)
    float* agg    = xs + (size_t)n * 128;       // n*128
    float* dinv   = agg + (size_t)n * 128;      // n
    float* logits = dinv + n;                   // n
    float2* part  = (float2*)(logits + n);      // 64 float2
    float* gms    = (float*)(part + 64);        // 2
    int* deg      = (int*)(gms + 2);            // n
    int* rowptr   = deg + n;                    // n+1
    int* cursor   = rowptr + n + 1;             // n
    int* csrsrc   = cursor + n;                 // E

    hipMemsetAsync(deg, 0, sizeof(int) * (size_t)(3 * n + 1), stream);
    hipMemsetAsync(out + (size_t)n * 256, 0, sizeof(float) * 256, stream);

    count_deg_kernel<<<(E + 255) / 256, 256, 0, stream>>>(dstA, E, deg);
    scan_kernel<<<1, 1024, 0, stream>>>(deg, rowptr, n);
    scatter_kernel<<<(E + 255) / 256, 256, 0, stream>>>(srcA, dstA, E, rowptr, cursor, csrsrc);
    dinv_prescale_kernel<<<(n + 3) / 4, 256, 0, stream>>>(x, deg, dinv, xs, n);

    int aggBlocks = (n + 7) / 8;
    int gemmBlocks = (n + 63) / 64;

    // layer 1: aggregate prescaled x, then GEMM; epilogue writes h1s = dinv*relu(.) into xs buffer
    aggregate_kernel<<<aggBlocks, 256, 0, stream>>>(xs, dinv, rowptr, deg, csrsrc, agg, n);
    gemm_bias_relu<128, true, false><<<gemmBlocks, 256, 0, stream>>>(agg, W1, b1, xs, n, dinv,
                                                                     nullptr, nullptr, nullptr);
    // layer 2: aggregate h1s, GEMM to node embeddings (d_out) with fused logits
    aggregate_kernel<<<aggBlocks, 256, 0, stream>>>(xs, dinv, rowptr, deg, csrsrc, agg, n);
    gemm_bias_relu<256, false, true><<<gemmBlocks, 256, 0, stream>>>(agg, W2, b2, out, n, nullptr,
                                                                     Wa, ba, logits);

    maxsum_kernel<<<64, 256, 0, stream>>>(logits, n, part);
    merge_kernel<<<1, 64, 0, stream>>>(part, gms);
    weighted_sum_kernel<<<512, 256, 0, stream>>>(out, logits, gms, out + (size_t)n * 256, n);
    normalize_kernel<<<1, 256, 0, stream>>>(out + (size_t)n * 256, gms);
}

// Round 3
// 487.538 us; speedup vs baseline: 1.2351x; 1.1174x over previous
//
#include <hip/hip_runtime.h>
#include <math.h>

typedef __attribute__((ext_vector_type(8))) short bf16x8;
typedef __attribute__((ext_vector_type(4))) float f32x4;

static __device__ __forceinline__ unsigned short f2bf(float x) {
    unsigned u = __float_as_uint(x);
    unsigned r = (u + 0x7FFF + ((u >> 16) & 1)) >> 16;
    return (unsigned short)r;
}
static __device__ __forceinline__ float bf2f(unsigned short h) {
    return __uint_as_float(((unsigned)h) << 16);
}

// ---------------- CSR build ----------------

__global__ __launch_bounds__(256) void count_deg_kernel(const int* __restrict__ dst, int E,
                                                        int* __restrict__ deg) {
    int e = blockIdx.x * 256 + threadIdx.x;
    if (e < E) atomicAdd(&deg[dst[e]], 1);
}

__global__ __launch_bounds__(1024) void scan_kernel(const int* __restrict__ deg,
                                                    int* __restrict__ rowptr, int n) {
    __shared__ int sm[1024];
    int t = threadIdx.x;
    int ch = (n + 1023) >> 10;
    int start = t * ch;
    int end = min(start + ch, n);
    int s = 0;
    for (int i = start; i < end; ++i) s += deg[i];
    sm[t] = s;
    __syncthreads();
    for (int off = 1; off < 1024; off <<= 1) {
        int v = (t >= off) ? sm[t - off] : 0;
        __syncthreads();
        sm[t] += v;
        __syncthreads();
    }
    int run = (t > 0) ? sm[t - 1] : 0;
    for (int i = start; i < end; ++i) { rowptr[i] = run; run += deg[i]; }
    if (t == 1023) rowptr[n] = sm[1023];
}

__global__ __launch_bounds__(256) void scatter_kernel(const int* __restrict__ src,
                                                      const int* __restrict__ dst, int E,
                                                      const int* __restrict__ rowptr,
                                                      int* __restrict__ cursor,
                                                      int* __restrict__ csrsrc) {
    int e = blockIdx.x * 256 + threadIdx.x;
    if (e < E) {
        int d = dst[e];
        int pos = atomicAdd(&cursor[d], 1);
        csrsrc[rowptr[d] + pos] = src[e];
    }
}

// ---------------- dinv + prescale ----------------

__global__ __launch_bounds__(256) void dinv_prescale_kernel(const float* __restrict__ x,
                                                            const int* __restrict__ deg,
                                                            float* __restrict__ dinv,
                                                            float* __restrict__ xs, int n) {
    int node = blockIdx.x * 4 + (threadIdx.x >> 6);
    int lane = threadIdx.x & 63;
    if (node >= n) return;
    float di = rsqrtf((float)(deg[node] + 1));
    if (lane == 0) dinv[node] = di;
    float2 v = *(const float2*)(x + (size_t)node * 128 + (lane << 1));
    *(float2*)(xs + (size_t)node * 128 + (lane << 1)) = make_float2(di * v.x, di * v.y);
}

// ---------------- W transpose + bf16 split: Wt[n][k] planes ----------------

__global__ __launch_bounds__(256) void wconvert_kernel(const float* __restrict__ W1,
                                                       const float* __restrict__ W2,
                                                       unsigned short* __restrict__ w1h,
                                                       unsigned short* __restrict__ w1l,
                                                       unsigned short* __restrict__ w2h,
                                                       unsigned short* __restrict__ w2l) {
    int i = blockIdx.x * 256 + threadIdx.x;
    if (i < 128 * 128) {
        int nn = i >> 7, k = i & 127;
        float v = W1[k * 128 + nn];
        unsigned short h = f2bf(v);
        w1h[i] = h;
        w1l[i] = f2bf(v - bf2f(h));
    } else if (i < 128 * 128 + 256 * 128) {
        int j = i - 128 * 128;
        int nn = j >> 7, k = j & 127;
        float v = W2[k * 256 + nn];
        unsigned short h = f2bf(v);
        w2h[j] = h;
        w2l[j] = f2bf(v - bf2f(h));
    }
}

// ---------------- aggregation -> split-bf16 planes ----------------
// outH/outL[i] = split_bf16( dinv[i] * ( xs[i] + sum_e xs[src_e] ) )

__global__ __launch_bounds__(256) void aggregate_kernel(const float* __restrict__ Xs,
                                                        const float* __restrict__ dinv,
                                                        const int* __restrict__ rowptr,
                                                        const int* __restrict__ deg,
                                                        const int* __restrict__ csrsrc,
                                                        unsigned short* __restrict__ outH,
                                                        unsigned short* __restrict__ outL, int n) {
    int node = blockIdx.x * 8 + (threadIdx.x >> 5);
    int sl = threadIdx.x & 31;
    if (node >= n) return;
    const float4* Xv = (const float4*)Xs;
    float4 acc = Xv[(size_t)node * 32 + sl];
    int e0 = rowptr[node];
    int e1 = e0 + deg[node];
    int e = e0;
    for (; e + 4 <= e1; e += 4) {
        int s0 = csrsrc[e], s1 = csrsrc[e + 1], s2 = csrsrc[e + 2], s3 = csrsrc[e + 3];
        float4 v0 = Xv[(size_t)s0 * 32 + sl];
        float4 v1 = Xv[(size_t)s1 * 32 + sl];
        float4 v2 = Xv[(size_t)s2 * 32 + sl];
        float4 v3 = Xv[(size_t)s3 * 32 + sl];
        acc.x += (v0.x + v1.x) + (v2.x + v3.x);
        acc.y += (v0.y + v1.y) + (v2.y + v3.y);
        acc.z += (v0.z + v1.z) + (v2.z + v3.z);
        acc.w += (v0.w + v1.w) + (v2.w + v3.w);
    }
    for (; e < e1; ++e) {
        int s = csrsrc[e];
        float4 v = Xv[(size_t)s * 32 + sl];
        acc.x += v.x; acc.y += v.y; acc.z += v.z; acc.w += v.w;
    }
    float di = dinv[node];
    float f0 = di * acc.x, f1 = di * acc.y, f2 = di * acc.z, f3 = di * acc.w;
    ushort4 hv, lv;
    hv.x = f2bf(f0); lv.x = f2bf(f0 - bf2f(hv.x));
    hv.y = f2bf(f1); lv.y = f2bf(f1 - bf2f(hv.y));
    hv.z = f2bf(f2); lv.z = f2bf(f2 - bf2f(hv.z));
    hv.w = f2bf(f3); lv.w = f2bf(f3 - bf2f(hv.w));
    *(ushort4*)(outH + (size_t)node * 128 + (sl << 2)) = hv;
    *(ushort4*)(outL + (size_t)node * 128 + (sl << 2)) = lv;
}

// ---------------- split-bf16 MFMA GEMM ----------------
// C[M x N] = relu( A[M x 128] @ W[128 x N] + b ) [* dinv[row]] ; optional fused logits atomics.
// A given as hi/lo bf16 planes (row-major M x 128); W given as TRANSPOSED hi/lo planes [N][128].
// Block: 256 thr = 4 waves (2x2), block tile 128x128, wave tile 64x64 (4x4 MFMA 16x16x32 tiles).
// K chunked BK=64; LDS 64 KB -> 2 blocks/CU. XOR-swizzled 16B granules, conflict-free b128 frags.

template <int N, bool SCALE_DINV, bool DO_LOGITS>
__global__ __launch_bounds__(256, 2) void gemm_mfma(const unsigned short* __restrict__ Ah,
                                                    const unsigned short* __restrict__ Al,
                                                    const unsigned short* __restrict__ Bth,
                                                    const unsigned short* __restrict__ Btl,
                                                    const float* __restrict__ bias,
                                                    float* __restrict__ C, int M,
                                                    const float* __restrict__ dinv,
                                                    const float* __restrict__ Wa,
                                                    float* __restrict__ logits) {
    __shared__ unsigned short AsH[128 * 64];
    __shared__ unsigned short AsL[128 * 64];
    __shared__ unsigned short BsH[128 * 64];
    __shared__ unsigned short BsL[128 * 64];

    const int t = threadIdx.x;
    const int lane = t & 63;
    const int wave = t >> 6;
    const int wrow = wave >> 1;         // 0..1
    const int wcol = wave & 1;          // 0..1
    const int lq = lane >> 4;           // quad 0..3
    const int lm = lane & 15;
    const int row0 = blockIdx.x * 128;
    const int col0 = blockIdx.y * 128;

    f32x4 acc[4][4] = {};
    float lacc[4][4] = {};

    for (int kc = 0; kc < 2; ++kc) {
        __syncthreads();
        // stage A planes: 128 rows x 8 granules (16B) each plane
#pragma unroll
        for (int i = 0; i < 4; ++i) {
            int idx = t + i * 256;      // 0..1023
            int r = idx >> 3;
            int g = idx & 7;
            int gr = row0 + r;
            uint4 vh = make_uint4(0, 0, 0, 0), vl = make_uint4(0, 0, 0, 0);
            if (gr < M) {
                const size_t go = (size_t)gr * 128 + kc * 64 + g * 8;
                vh = *(const uint4*)(Ah + go);
                vl = *(const uint4*)(Al + go);
            }
            int sg = g ^ (r & 7);
            *(uint4*)(AsH + r * 64 + sg * 8) = vh;
            *(uint4*)(AsL + r * 64 + sg * 8) = vl;
        }
        // stage B planes: 128 n-rows x 8 granules
#pragma unroll
        for (int i = 0; i < 4; ++i) {
            int idx = t + i * 256;
            int nn = idx >> 3;
            int g = idx & 7;
            const size_t go = (size_t)(col0 + nn) * 128 + kc * 64 + g * 8;
            int sg = g ^ (nn & 7);
            *(uint4*)(BsH + nn * 64 + sg * 8) = *(const uint4*)(Bth + go);
            *(uint4*)(BsL + nn * 64 + sg * 8) = *(const uint4*)(Btl + go);
        }
        __syncthreads();

#pragma unroll
        for (int ks = 0; ks < 2; ++ks) {
            bf16x8 ah[4], al[4], bh[4], bl[4];
            int gbase = ks * 4 + lq;
#pragma unroll
            for (int rt = 0; rt < 4; ++rt) {
                int ra = wrow * 64 + rt * 16 + lm;
                int off = ra * 64 + (gbase ^ (ra & 7)) * 8;
                ah[rt] = *(const bf16x8*)(AsH + off);
                al[rt] = *(const bf16x8*)(AsL + off);
            }
#pragma unroll
            for (int ct = 0; ct < 4; ++ct) {
                int nb = wcol * 64 + ct * 16 + lm;
                int off = nb * 64 + (gbase ^ (nb & 7)) * 8;
                bh[ct] = *(const bf16x8*)(BsH + off);
                bl[ct] = *(const bf16x8*)(BsL + off);
            }
#pragma unroll
            for (int rt = 0; rt < 4; ++rt)
#pragma unroll
                for (int ct = 0; ct < 4; ++ct) {
                    acc[rt][ct] = __builtin_amdgcn_mfma_f32_16x16x32_bf16(ah[rt], bh[ct], acc[rt][ct], 0, 0, 0);
                    acc[rt][ct] = __builtin_amdgcn_mfma_f32_16x16x32_bf16(al[rt], bh[ct], acc[rt][ct], 0, 0, 0);
                    acc[rt][ct] = __builtin_amdgcn_mfma_f32_16x16x32_bf16(ah[rt], bl[ct], acc[rt][ct], 0, 0, 0);
                }
        }
    }

    // epilogue: C/D frag layout col = lm, row = lq*4 + reg
#pragma unroll
    for (int ct = 0; ct < 4; ++ct) {
        int col = col0 + wcol * 64 + ct * 16 + lm;
        float bc = bias[col];
        float wac = DO_LOGITS ? Wa[col] : 0.f;
#pragma unroll
        for (int rt = 0; rt < 4; ++rt) {
            int rowb = row0 + wrow * 64 + rt * 16 + lq * 4;
#pragma unroll
            for (int reg = 0; reg < 4; ++reg) {
                int gr = rowb + reg;
                if (gr < M) {
                    float o = fmaxf(acc[rt][ct][reg] + bc, 0.f);
                    if (SCALE_DINV) o *= dinv[gr];
                    C[(size_t)gr * N + col] = o;
                    if (DO_LOGITS) lacc[rt][reg] += o * wac;
                }
            }
        }
    }

    if (DO_LOGITS) {
#pragma unroll
        for (int rt = 0; rt < 4; ++rt)
#pragma unroll
            for (int reg = 0; reg < 4; ++reg) {
                float s = lacc[rt][reg];
                s += __shfl_xor(s, 1);
                s += __shfl_xor(s, 2);
                s += __shfl_xor(s, 4);
                s += __shfl_xor(s, 8);
                int gr = row0 + wrow * 64 + rt * 16 + lq * 4 + reg;
                if (lm == 0 && gr < M) atomicAdd(&logits[gr], s);
            }
    }
}

// ---------------- attention pooling ----------------

__global__ __launch_bounds__(256) void maxsum_kernel(const float* __restrict__ logits, int n,
                                                     float2* __restrict__ part) {
    float m = -INFINITY, s = 0.f;
    for (int i = blockIdx.x * 256 + threadIdx.x; i < n; i += gridDim.x * 256) {
        float v = logits[i];
        if (v > m) { s = s * expf(m - v) + 1.f; m = v; }
        else s += expf(v - m);
    }
    __shared__ float sm[256], ss[256];
    sm[threadIdx.x] = m; ss[threadIdx.x] = s;
    __syncthreads();
    for (int off = 128; off > 0; off >>= 1) {
        if (threadIdx.x < off) {
            float m1 = sm[threadIdx.x], s1 = ss[threadIdx.x];
            float m2 = sm[threadIdx.x + off], s2 = ss[threadIdx.x + off];
            float M = fmaxf(m1, m2);
            sm[threadIdx.x] = M;
            ss[threadIdx.x] = s1 * expf(m1 - M) + s2 * expf(m2 - M);
        }
        __syncthreads();
    }
    if (threadIdx.x == 0) part[blockIdx.x] = make_float2(sm[0], ss[0]);
}

__global__ __launch_bounds__(64) void merge_kernel(const float2* __restrict__ part,
                                                   float* __restrict__ gms) {
    __shared__ float sm[64], ss[64];
    float2 p = part[threadIdx.x];
    sm[threadIdx.x] = p.x; ss[threadIdx.x] = p.y;
    __syncthreads();
    for (int off = 32; off > 0; off >>= 1) {
        if (threadIdx.x < off) {
            float m1 = sm[threadIdx.x], s1 = ss[threadIdx.x];
            float m2 = sm[threadIdx.x + off], s2 = ss[threadIdx.x + off];
            float M = fmaxf(m1, m2);
            sm[threadIdx.x] = M;
            ss[threadIdx.x] = s1 * expf(m1 - M) + s2 * expf(m2 - M);
        }
        __syncthreads();
    }
    if (threadIdx.x == 0) { gms[0] = sm[0]; gms[1] = ss[0]; }
}

__global__ __launch_bounds__(256) void weighted_sum_kernel(const float* __restrict__ emb,
                                                           const float* __restrict__ logits,
                                                           const float* __restrict__ gms,
                                                           float* __restrict__ outTail, int n) {
    float g = gms[0];
    int c = threadIdx.x;
    float acc = 0.f;
    for (int i = blockIdx.x; i < n; i += gridDim.x) {
        float w = expf(logits[i] - g);
        acc += w * emb[(size_t)i * 256 + c];
    }
    atomicAdd(&outTail[c], acc);
}

__global__ __launch_bounds__(256) void normalize_kernel(float* __restrict__ outTail,
                                                        const float* __restrict__ gms) {
    outTail[threadIdx.x] = outTail[threadIdx.x] / gms[1];
}

// ---------------- launch ----------------

extern "C" void kernel_launch(void* const* d_in, const int* in_sizes, int n_in,
                              void* d_out, int out_size, void* d_ws, size_t ws_size,
                              hipStream_t stream) {
    const float* x  = (const float*)d_in[0];
    const int* ei   = (const int*)d_in[1];
    const float* W1 = (const float*)d_in[2];
    const float* b1 = (const float*)d_in[3];
    const float* W2 = (const float*)d_in[4];
    const float* b2 = (const float*)d_in[5];
    const float* Wa = (const float*)d_in[6];
    float* out = (float*)d_out;

    const int n = in_sizes[0] / 128;  // 50000
    const int E = in_sizes[1] / 2;    // 800000
    const int* srcA = ei;
    const int* dstA = ei + E;

    // workspace layout
    float* ws     = (float*)d_ws;
    float* xs     = ws;                                   // n*128 fp32 (prescaled x, then h1s)
    unsigned short* aggH = (unsigned short*)(xs + (size_t)n * 128);  // n*128 bf16
    unsigned short* aggL = aggH + (size_t)n * 128;
    unsigned short* w1h  = aggL + (size_t)n * 128;        // 128*128
    unsigned short* w1l  = w1h + 128 * 128;
    unsigned short* w2h  = w1l + 128 * 128;               // 256*128
    unsigned short* w2l  = w2h + 256 * 128;
    float* dinv   = (float*)(w2l + 256 * 128);            // n
    float* logits = dinv + n;                             // n
    float2* part  = (float2*)(logits + n);                // 64
    float* gms    = (float*)(part + 64);                  // 2
    int* deg      = (int*)(gms + 2);                      // n
    int* rowptr   = deg + n;                              // n+1
    int* cursor   = rowptr + n + 1;                       // n
    int* csrsrc   = cursor + n;                           // E

    hipMemsetAsync(deg, 0, sizeof(int) * (size_t)(3 * n + 1), stream);
    hipMemsetAsync(logits, 0, sizeof(float) * (size_t)n, stream);
    hipMemsetAsync(out + (size_t)n * 256, 0, sizeof(float) * 256, stream);

    count_deg_kernel<<<(E + 255) / 256, 256, 0, stream>>>(dstA, E, deg);
    scan_kernel<<<1, 1024, 0, stream>>>(deg, rowptr, n);
    scatter_kernel<<<(E + 255) / 256, 256, 0, stream>>>(srcA, dstA, E, rowptr, cursor, csrsrc);
    dinv_prescale_kernel<<<(n + 3) / 4, 256, 0, stream>>>(x, deg, dinv, xs, n);
    wconvert_kernel<<<(128 * 128 + 256 * 128 + 255) / 256, 256, 0, stream>>>(W1, W2, w1h, w1l, w2h, w2l);

    int aggBlocks = (n + 7) / 8;
    int gemmRows = (n + 127) / 128;

    // layer 1
    aggregate_kernel<<<aggBlocks, 256, 0, stream>>>(xs, dinv, rowptr, deg, csrsrc, aggH, aggL, n);
    gemm_mfma<128, true, false><<<dim3(gemmRows, 1), 256, 0, stream>>>(aggH, aggL, w1h, w1l, b1,
                                                                       xs, n, dinv, nullptr, nullptr);
    // layer 2 (+fused logits; ba cancels in softmax)
    aggregate_kernel<<<aggBlocks, 256, 0, stream>>>(xs, dinv, rowptr, deg, csrsrc, aggH, aggL, n);
    gemm_mfma<256, false, true><<<dim3(gemmRows, 2), 256, 0, stream>>>(aggH, aggL, w2h, w2l, b2,
                                                                       out, n, nullptr, Wa, logits);

    maxsum_kernel<<<64, 256, 0, stream>>>(logits, n, part);
    merge_kernel<<<1, 64, 0, stream>>>(part, gms);
    weighted_sum_kernel<<<512, 256, 0, stream>>>(out, logits, gms, out + (size_t)n * 256, n);
    normalize_kernel<<<1, 256, 0, stream>>>(out + (size_t)n * 256, gms);
}

// Round 4
// 419.563 us; speedup vs baseline: 1.4352x; 1.1620x over previous
//
#include <hip/hip_runtime.h>
#include <math.h>

typedef __attribute__((ext_vector_type(8))) short bf16x8;
typedef __attribute__((ext_vector_type(4))) float f32x4;

static __device__ __forceinline__ unsigned short f2bf(float x) {
    unsigned u = __float_as_uint(x);
    unsigned r = (u + 0x7FFF + ((u >> 16) & 1)) >> 16;
    return (unsigned short)r;
}
static __device__ __forceinline__ float bf2f(unsigned short h) {
    return __uint_as_float(((unsigned)h) << 16);
}

// ---------------- CSR build ----------------

__global__ __launch_bounds__(256) void count_deg_kernel(const int* __restrict__ dst, int E,
                                                        int* __restrict__ deg) {
    int e = blockIdx.x * 256 + threadIdx.x;
    if (e < E) atomicAdd(&deg[dst[e]], 1);
}

// ---- hierarchical exclusive scan of deg[0..n) -> rowptr[0..n], coalesced ----

__global__ __launch_bounds__(256) void scan_partial_kernel(const int* __restrict__ deg, int n,
                                                           int* __restrict__ partials) {
    int idx = blockIdx.x * 1024 + threadIdx.x * 4;
    int4 v = make_int4(0, 0, 0, 0);
    if (idx + 3 < n) v = *(const int4*)(deg + idx);
    else {
        if (idx < n) v.x = deg[idx];
        if (idx + 1 < n) v.y = deg[idx + 1];
        if (idx + 2 < n) v.z = deg[idx + 2];
    }
    int s = v.x + v.y + v.z + v.w;
    for (int off = 1; off < 64; off <<= 1) s += __shfl_xor(s, off);
    __shared__ int sm[4];
    int wave = threadIdx.x >> 6;
    if ((threadIdx.x & 63) == 0) sm[wave] = s;
    __syncthreads();
    if (threadIdx.x == 0) partials[blockIdx.x] = sm[0] + sm[1] + sm[2] + sm[3];
}

// one wave: exclusive scan of nb (<=64) partials -> poff; writes rowptr[n] = total
__global__ __launch_bounds__(64) void scan_offsets_kernel(const int* __restrict__ partials, int nb,
                                                          int* __restrict__ poff,
                                                          int* __restrict__ rowptr, int n) {
    int t = threadIdx.x;
    int v = (t < nb) ? partials[t] : 0;
    int s = v;
    for (int off = 1; off < 64; off <<= 1) {
        int u = __shfl_up(s, off);
        if (t >= off) s += u;
    }
    poff[t] = s - v;
    if (t == 63) rowptr[n] = s;
}

__global__ __launch_bounds__(256) void scan_final_kernel(const int* __restrict__ deg, int n,
                                                         const int* __restrict__ poff,
                                                         int* __restrict__ rowptr) {
    int idx = blockIdx.x * 1024 + threadIdx.x * 4;
    int4 v = make_int4(0, 0, 0, 0);
    if (idx + 3 < n) v = *(const int4*)(deg + idx);
    else {
        if (idx < n) v.x = deg[idx];
        if (idx + 1 < n) v.y = deg[idx + 1];
        if (idx + 2 < n) v.z = deg[idx + 2];
    }
    int tsum = v.x + v.y + v.z + v.w;
    int lane = threadIdx.x & 63, wave = threadIdx.x >> 6;
    int s = tsum;
    for (int off = 1; off < 64; off <<= 1) {
        int u = __shfl_up(s, off);
        if (lane >= off) s += u;
    }
    __shared__ int wsum[4];
    if (lane == 63) wsum[wave] = s;
    __syncthreads();
    int base = poff[blockIdx.x];
    for (int w = 0; w < wave; ++w) base += wsum[w];
    int e0 = base + s - tsum;
    int4 o;
    o.x = e0; o.y = e0 + v.x; o.z = o.y + v.y; o.w = o.z + v.z;
    if (idx + 3 < n) *(int4*)(rowptr + idx) = o;
    else {
        if (idx < n) rowptr[idx] = o.x;
        if (idx + 1 < n) rowptr[idx + 1] = o.y;
        if (idx + 2 < n) rowptr[idx + 2] = o.z;
    }
}

__global__ __launch_bounds__(256) void scatter_kernel(const int* __restrict__ src,
                                                      const int* __restrict__ dst, int E,
                                                      const int* __restrict__ rowptr,
                                                      int* __restrict__ cursor,
                                                      int* __restrict__ csrsrc) {
    int e = blockIdx.x * 256 + threadIdx.x;
    if (e < E) {
        int d = dst[e];
        int pos = atomicAdd(&cursor[d], 1);
        csrsrc[rowptr[d] + pos] = src[e];
    }
}

// ---------------- dinv + prescale ----------------

__global__ __launch_bounds__(256) void dinv_prescale_kernel(const float* __restrict__ x,
                                                            const int* __restrict__ deg,
                                                            float* __restrict__ dinv,
                                                            float* __restrict__ xs, int n) {
    int node = blockIdx.x * 4 + (threadIdx.x >> 6);
    int lane = threadIdx.x & 63;
    if (node >= n) return;
    float di = rsqrtf((float)(deg[node] + 1));
    if (lane == 0) dinv[node] = di;
    float2 v = *(const float2*)(x + (size_t)node * 128 + (lane << 1));
    *(float2*)(xs + (size_t)node * 128 + (lane << 1)) = make_float2(di * v.x, di * v.y);
}

// ---------------- W transpose + bf16 split: Wt[n][k] planes ----------------

__global__ __launch_bounds__(256) void wconvert_kernel(const float* __restrict__ W1,
                                                       const float* __restrict__ W2,
                                                       unsigned short* __restrict__ w1h,
                                                       unsigned short* __restrict__ w1l,
                                                       unsigned short* __restrict__ w2h,
                                                       unsigned short* __restrict__ w2l) {
    int i = blockIdx.x * 256 + threadIdx.x;
    if (i < 128 * 128) {
        int nn = i >> 7, k = i & 127;
        float v = W1[k * 128 + nn];
        unsigned short h = f2bf(v);
        w1h[i] = h;
        w1l[i] = f2bf(v - bf2f(h));
    } else if (i < 128 * 128 + 256 * 128) {
        int j = i - 128 * 128;
        int nn = j >> 7, k = j & 127;
        float v = W2[k * 256 + nn];
        unsigned short h = f2bf(v);
        w2h[j] = h;
        w2l[j] = f2bf(v - bf2f(h));
    }
}

// ---------------- aggregation -> split-bf16 planes ----------------
// outH/outL[i] = split_bf16( dinv[i] * ( xs[i] + sum_e xs[src_e] ) )

__global__ __launch_bounds__(256) void aggregate_kernel(const float* __restrict__ Xs,
                                                        const float* __restrict__ dinv,
                                                        const int* __restrict__ rowptr,
                                                        const int* __restrict__ deg,
                                                        const int* __restrict__ csrsrc,
                                                        unsigned short* __restrict__ outH,
                                                        unsigned short* __restrict__ outL, int n) {
    int node = blockIdx.x * 8 + (threadIdx.x >> 5);
    int sl = threadIdx.x & 31;
    if (node >= n) return;
    const float4* Xv = (const float4*)Xs;
    float4 acc = Xv[(size_t)node * 32 + sl];
    int e0 = rowptr[node];
    int e1 = e0 + deg[node];
    int e = e0;
    for (; e + 4 <= e1; e += 4) {
        int s0 = csrsrc[e], s1 = csrsrc[e + 1], s2 = csrsrc[e + 2], s3 = csrsrc[e + 3];
        float4 v0 = Xv[(size_t)s0 * 32 + sl];
        float4 v1 = Xv[(size_t)s1 * 32 + sl];
        float4 v2 = Xv[(size_t)s2 * 32 + sl];
        float4 v3 = Xv[(size_t)s3 * 32 + sl];
        acc.x += (v0.x + v1.x) + (v2.x + v3.x);
        acc.y += (v0.y + v1.y) + (v2.y + v3.y);
        acc.z += (v0.z + v1.z) + (v2.z + v3.z);
        acc.w += (v0.w + v1.w) + (v2.w + v3.w);
    }
    for (; e < e1; ++e) {
        int s = csrsrc[e];
        float4 v = Xv[(size_t)s * 32 + sl];
        acc.x += v.x; acc.y += v.y; acc.z += v.z; acc.w += v.w;
    }
    float di = dinv[node];
    float f0 = di * acc.x, f1 = di * acc.y, f2 = di * acc.z, f3 = di * acc.w;
    ushort4 hv, lv;
    hv.x = f2bf(f0); lv.x = f2bf(f0 - bf2f(hv.x));
    hv.y = f2bf(f1); lv.y = f2bf(f1 - bf2f(hv.y));
    hv.z = f2bf(f2); lv.z = f2bf(f2 - bf2f(hv.z));
    hv.w = f2bf(f3); lv.w = f2bf(f3 - bf2f(hv.w));
    *(ushort4*)(outH + (size_t)node * 128 + (sl << 2)) = hv;
    *(ushort4*)(outL + (size_t)node * 128 + (sl << 2)) = lv;
}

// ---------------- split-bf16 MFMA GEMM ----------------

template <int N, bool SCALE_DINV, bool DO_LOGITS>
__global__ __launch_bounds__(256, 2) void gemm_mfma(const unsigned short* __restrict__ Ah,
                                                    const unsigned short* __restrict__ Al,
                                                    const unsigned short* __restrict__ Bth,
                                                    const unsigned short* __restrict__ Btl,
                                                    const float* __restrict__ bias,
                                                    float* __restrict__ C, int M,
                                                    const float* __restrict__ dinv,
                                                    const float* __restrict__ Wa,
                                                    float* __restrict__ logits) {
    __shared__ unsigned short AsH[128 * 64];
    __shared__ unsigned short AsL[128 * 64];
    __shared__ unsigned short BsH[128 * 64];
    __shared__ unsigned short BsL[128 * 64];

    const int t = threadIdx.x;
    const int lane = t & 63;
    const int wave = t >> 6;
    const int wrow = wave >> 1;
    const int wcol = wave & 1;
    const int lq = lane >> 4;
    const int lm = lane & 15;
    const int row0 = blockIdx.x * 128;
    const int col0 = blockIdx.y * 128;

    f32x4 acc[4][4] = {};
    float lacc[4][4] = {};

    for (int kc = 0; kc < 2; ++kc) {
        __syncthreads();
#pragma unroll
        for (int i = 0; i < 4; ++i) {
            int idx = t + i * 256;
            int r = idx >> 3;
            int g = idx & 7;
            int gr = row0 + r;
            uint4 vh = make_uint4(0, 0, 0, 0), vl = make_uint4(0, 0, 0, 0);
            if (gr < M) {
                const size_t go = (size_t)gr * 128 + kc * 64 + g * 8;
                vh = *(const uint4*)(Ah + go);
                vl = *(const uint4*)(Al + go);
            }
            int sg = g ^ (r & 7);
            *(uint4*)(AsH + r * 64 + sg * 8) = vh;
            *(uint4*)(AsL + r * 64 + sg * 8) = vl;
        }
#pragma unroll
        for (int i = 0; i < 4; ++i) {
            int idx = t + i * 256;
            int nn = idx >> 3;
            int g = idx & 7;
            const size_t go = (size_t)(col0 + nn) * 128 + kc * 64 + g * 8;
            int sg = g ^ (nn & 7);
            *(uint4*)(BsH + nn * 64 + sg * 8) = *(const uint4*)(Bth + go);
            *(uint4*)(BsL + nn * 64 + sg * 8) = *(const uint4*)(Btl + go);
        }
        __syncthreads();

#pragma unroll
        for (int ks = 0; ks < 2; ++ks) {
            bf16x8 ah[4], al[4], bh[4], bl[4];
            int gbase = ks * 4 + lq;
#pragma unroll
            for (int rt = 0; rt < 4; ++rt) {
                int ra = wrow * 64 + rt * 16 + lm;
                int off = ra * 64 + (gbase ^ (ra & 7)) * 8;
                ah[rt] = *(const bf16x8*)(AsH + off);
                al[rt] = *(const bf16x8*)(AsL + off);
            }
#pragma unroll
            for (int ct = 0; ct < 4; ++ct) {
                int nb = wcol * 64 + ct * 16 + lm;
                int off = nb * 64 + (gbase ^ (nb & 7)) * 8;
                bh[ct] = *(const bf16x8*)(BsH + off);
                bl[ct] = *(const bf16x8*)(BsL + off);
            }
#pragma unroll
            for (int rt = 0; rt < 4; ++rt)
#pragma unroll
                for (int ct = 0; ct < 4; ++ct) {
                    acc[rt][ct] = __builtin_amdgcn_mfma_f32_16x16x32_bf16(ah[rt], bh[ct], acc[rt][ct], 0, 0, 0);
                    acc[rt][ct] = __builtin_amdgcn_mfma_f32_16x16x32_bf16(al[rt], bh[ct], acc[rt][ct], 0, 0, 0);
                    acc[rt][ct] = __builtin_amdgcn_mfma_f32_16x16x32_bf16(ah[rt], bl[ct], acc[rt][ct], 0, 0, 0);
                }
        }
    }

#pragma unroll
    for (int ct = 0; ct < 4; ++ct) {
        int col = col0 + wcol * 64 + ct * 16 + lm;
        float bc = bias[col];
        float wac = DO_LOGITS ? Wa[col] : 0.f;
#pragma unroll
        for (int rt = 0; rt < 4; ++rt) {
            int rowb = row0 + wrow * 64 + rt * 16 + lq * 4;
#pragma unroll
            for (int reg = 0; reg < 4; ++reg) {
                int gr = rowb + reg;
                if (gr < M) {
                    float o = fmaxf(acc[rt][ct][reg] + bc, 0.f);
                    if (SCALE_DINV) o *= dinv[gr];
                    C[(size_t)gr * N + col] = o;
                    if (DO_LOGITS) lacc[rt][reg] += o * wac;
                }
            }
        }
    }

    if (DO_LOGITS) {
#pragma unroll
        for (int rt = 0; rt < 4; ++rt)
#pragma unroll
            for (int reg = 0; reg < 4; ++reg) {
                float s = lacc[rt][reg];
                s += __shfl_xor(s, 1);
                s += __shfl_xor(s, 2);
                s += __shfl_xor(s, 4);
                s += __shfl_xor(s, 8);
                int gr = row0 + wrow * 64 + rt * 16 + lq * 4 + reg;
                if (lm == 0 && gr < M) atomicAdd(&logits[gr], s);
            }
    }
}

// ---------------- attention pooling ----------------

__global__ __launch_bounds__(256) void maxsum_kernel(const float* __restrict__ logits, int n,
                                                     float2* __restrict__ part) {
    float m = -INFINITY, s = 0.f;
    for (int i = blockIdx.x * 256 + threadIdx.x; i < n; i += gridDim.x * 256) {
        float v = logits[i];
        if (v > m) { s = s * expf(m - v) + 1.f; m = v; }
        else s += expf(v - m);
    }
    __shared__ float sm[256], ss[256];
    sm[threadIdx.x] = m; ss[threadIdx.x] = s;
    __syncthreads();
    for (int off = 128; off > 0; off >>= 1) {
        if (threadIdx.x < off) {
            float m1 = sm[threadIdx.x], s1 = ss[threadIdx.x];
            float m2 = sm[threadIdx.x + off], s2 = ss[threadIdx.x + off];
            float M = fmaxf(m1, m2);
            sm[threadIdx.x] = M;
            ss[threadIdx.x] = s1 * expf(m1 - M) + s2 * expf(m2 - M);
        }
        __syncthreads();
    }
    if (threadIdx.x == 0) part[blockIdx.x] = make_float2(sm[0], ss[0]);
}

__global__ __launch_bounds__(64) void merge_kernel(const float2* __restrict__ part,
                                                   float* __restrict__ gms) {
    __shared__ float sm[64], ss[64];
    float2 p = part[threadIdx.x];
    sm[threadIdx.x] = p.x; ss[threadIdx.x] = p.y;
    __syncthreads();
    for (int off = 32; off > 0; off >>= 1) {
        if (threadIdx.x < off) {
            float m1 = sm[threadIdx.x], s1 = ss[threadIdx.x];
            float m2 = sm[threadIdx.x + off], s2 = ss[threadIdx.x + off];
            float M = fmaxf(m1, m2);
            sm[threadIdx.x] = M;
            ss[threadIdx.x] = s1 * expf(m1 - M) + s2 * expf(m2 - M);
        }
        __syncthreads();
    }
    if (threadIdx.x == 0) { gms[0] = sm[0]; gms[1] = ss[0]; }
}

__global__ __launch_bounds__(256) void weighted_sum_kernel(const float* __restrict__ emb,
                                                           const float* __restrict__ logits,
                                                           const float* __restrict__ gms,
                                                           float* __restrict__ outTail, int n) {
    float g = gms[0];
    int c = threadIdx.x;
    float acc = 0.f;
    for (int i = blockIdx.x; i < n; i += gridDim.x) {
        float w = expf(logits[i] - g);
        acc += w * emb[(size_t)i * 256 + c];
    }
    atomicAdd(&outTail[c], acc);
}

__global__ __launch_bounds__(256) void normalize_kernel(float* __restrict__ outTail,
                                                        const float* __restrict__ gms) {
    outTail[threadIdx.x] = outTail[threadIdx.x] / gms[1];
}

// ---------------- launch ----------------

extern "C" void kernel_launch(void* const* d_in, const int* in_sizes, int n_in,
                              void* d_out, int out_size, void* d_ws, size_t ws_size,
                              hipStream_t stream) {
    const float* x  = (const float*)d_in[0];
    const int* ei   = (const int*)d_in[1];
    const float* W1 = (const float*)d_in[2];
    const float* b1 = (const float*)d_in[3];
    const float* W2 = (const float*)d_in[4];
    const float* b2 = (const float*)d_in[5];
    const float* Wa = (const float*)d_in[6];
    float* out = (float*)d_out;

    const int n = in_sizes[0] / 128;  // 50000
    const int E = in_sizes[1] / 2;    // 800000
    const int* srcA = ei;
    const int* dstA = ei + E;
    const int nb = (n + 1023) / 1024;  // scan blocks (49)

    // workspace layout
    float* ws     = (float*)d_ws;
    float* xs     = ws;                                   // n*128 fp32
    unsigned short* aggH = (unsigned short*)(xs + (size_t)n * 128);  // n*128 bf16
    unsigned short* aggL = aggH + (size_t)n * 128;
    unsigned short* w1h  = aggL + (size_t)n * 128;        // 128*128
    unsigned short* w1l  = w1h + 128 * 128;
    unsigned short* w2h  = w1l + 128 * 128;               // 256*128
    unsigned short* w2l  = w2h + 256 * 128;
    float* dinv   = (float*)(w2l + 256 * 128);            // n
    float* logits = dinv + n;                             // n
    float2* part  = (float2*)(logits + n);                // 64
    float* gms    = (float*)(part + 64);                  // 2
    int* deg      = (int*)(gms + 2);                      // n
    int* rowptr   = deg + n;                              // n+1
    int* cursor   = rowptr + n + 1;                       // n
    int* partials = cursor + n;                           // 64
    int* poff     = partials + 64;                        // 64
    int* csrsrc   = poff + 64;                            // E

    hipMemsetAsync(deg, 0, sizeof(int) * (size_t)(3 * n + 1), stream);
    hipMemsetAsync(logits, 0, sizeof(float) * (size_t)n, stream);
    hipMemsetAsync(out + (size_t)n * 256, 0, sizeof(float) * 256, stream);

    count_deg_kernel<<<(E + 255) / 256, 256, 0, stream>>>(dstA, E, deg);
    scan_partial_kernel<<<nb, 256, 0, stream>>>(deg, n, partials);
    scan_offsets_kernel<<<1, 64, 0, stream>>>(partials, nb, poff, rowptr, n);
    scan_final_kernel<<<nb, 256, 0, stream>>>(deg, n, poff, rowptr);
    scatter_kernel<<<(E + 255) / 256, 256, 0, stream>>>(srcA, dstA, E, rowptr, cursor, csrsrc);
    dinv_prescale_kernel<<<(n + 3) / 4, 256, 0, stream>>>(x, deg, dinv, xs, n);
    wconvert_kernel<<<(128 * 128 + 256 * 128 + 255) / 256, 256, 0, stream>>>(W1, W2, w1h, w1l, w2h, w2l);

    int aggBlocks = (n + 7) / 8;
    int gemmRows = (n + 127) / 128;

    // layer 1
    aggregate_kernel<<<aggBlocks, 256, 0, stream>>>(xs, dinv, rowptr, deg, csrsrc, aggH, aggL, n);
    gemm_mfma<128, true, false><<<dim3(gemmRows, 1), 256, 0, stream>>>(aggH, aggL, w1h, w1l, b1,
                                                                       xs, n, dinv, nullptr, nullptr);
    // layer 2 (+fused logits)
    aggregate_kernel<<<aggBlocks, 256, 0, stream>>>(xs, dinv, rowptr, deg, csrsrc, aggH, aggL, n);
    gemm_mfma<256, false, true><<<dim3(gemmRows, 2), 256, 0, stream>>>(aggH, aggL, w2h, w2l, b2,
                                                                       out, n, nullptr, Wa, logits);

    maxsum_kernel<<<64, 256, 0, stream>>>(logits, n, part);
    merge_kernel<<<1, 64, 0, stream>>>(part, gms);
    weighted_sum_kernel<<<512, 256, 0, stream>>>(out, logits, gms, out + (size_t)n * 256, n);
    normalize_kernel<<<1, 256, 0, stream>>>(out + (size_t)n * 256, gms);
}

// Round 5
// 334.779 us; speedup vs baseline: 1.7987x; 1.2533x over previous
//
#include <hip/hip_runtime.h>
#include <hip/hip_fp16.h>
#include <math.h>

typedef __attribute__((ext_vector_type(8))) short bf16x8;
typedef __attribute__((ext_vector_type(4))) float f32x4;

static __device__ __forceinline__ unsigned short f2bf(float x) {
    unsigned u = __float_as_uint(x);
    unsigned r = (u + 0x7FFF + ((u >> 16) & 1)) >> 16;
    return (unsigned short)r;
}
static __device__ __forceinline__ float bf2f(unsigned short h) {
    return __uint_as_float(((unsigned)h) << 16);
}
static __device__ __forceinline__ void addh8(float a[8], uint4 v) {
    float2 f;
    f = __half22float2(*(const __half2*)&v.x); a[0] += f.x; a[1] += f.y;
    f = __half22float2(*(const __half2*)&v.y); a[2] += f.x; a[3] += f.y;
    f = __half22float2(*(const __half2*)&v.z); a[4] += f.x; a[5] += f.y;
    f = __half22float2(*(const __half2*)&v.w); a[6] += f.x; a[7] += f.y;
}

// ---------------- CSR build ----------------

// counts degree AND records each edge's slot within its dst bucket (epos)
__global__ __launch_bounds__(256) void count_deg_kernel(const int* __restrict__ dst, int E,
                                                        int* __restrict__ deg,
                                                        int* __restrict__ epos) {
    int e = blockIdx.x * 256 + threadIdx.x;
    if (e < E) epos[e] = atomicAdd(&deg[dst[e]], 1);
}

// ---- hierarchical exclusive scan of deg[0..n) -> rowptr[0..n], coalesced ----

__global__ __launch_bounds__(256) void scan_partial_kernel(const int* __restrict__ deg, int n,
                                                           int* __restrict__ partials) {
    int idx = blockIdx.x * 1024 + threadIdx.x * 4;
    int4 v = make_int4(0, 0, 0, 0);
    if (idx + 3 < n) v = *(const int4*)(deg + idx);
    else {
        if (idx < n) v.x = deg[idx];
        if (idx + 1 < n) v.y = deg[idx + 1];
        if (idx + 2 < n) v.z = deg[idx + 2];
    }
    int s = v.x + v.y + v.z + v.w;
    for (int off = 1; off < 64; off <<= 1) s += __shfl_xor(s, off);
    __shared__ int sm[4];
    int wave = threadIdx.x >> 6;
    if ((threadIdx.x & 63) == 0) sm[wave] = s;
    __syncthreads();
    if (threadIdx.x == 0) partials[blockIdx.x] = sm[0] + sm[1] + sm[2] + sm[3];
}

__global__ __launch_bounds__(64) void scan_offsets_kernel(const int* __restrict__ partials, int nb,
                                                          int* __restrict__ poff,
                                                          int* __restrict__ rowptr, int n) {
    int t = threadIdx.x;
    int v = (t < nb) ? partials[t] : 0;
    int s = v;
    for (int off = 1; off < 64; off <<= 1) {
        int u = __shfl_up(s, off);
        if (t >= off) s += u;
    }
    poff[t] = s - v;
    if (t == 63) rowptr[n] = s;
}

__global__ __launch_bounds__(256) void scan_final_kernel(const int* __restrict__ deg, int n,
                                                         const int* __restrict__ poff,
                                                         int* __restrict__ rowptr) {
    int idx = blockIdx.x * 1024 + threadIdx.x * 4;
    int4 v = make_int4(0, 0, 0, 0);
    if (idx + 3 < n) v = *(const int4*)(deg + idx);
    else {
        if (idx < n) v.x = deg[idx];
        if (idx + 1 < n) v.y = deg[idx + 1];
        if (idx + 2 < n) v.z = deg[idx + 2];
    }
    int tsum = v.x + v.y + v.z + v.w;
    int lane = threadIdx.x & 63, wave = threadIdx.x >> 6;
    int s = tsum;
    for (int off = 1; off < 64; off <<= 1) {
        int u = __shfl_up(s, off);
        if (lane >= off) s += u;
    }
    __shared__ int wsum[4];
    if (lane == 63) wsum[wave] = s;
    __syncthreads();
    int base = poff[blockIdx.x];
    for (int w = 0; w < wave; ++w) base += wsum[w];
    int e0 = base + s - tsum;
    int4 o;
    o.x = e0; o.y = e0 + v.x; o.z = o.y + v.y; o.w = o.z + v.z;
    if (idx + 3 < n) *(int4*)(rowptr + idx) = o;
    else {
        if (idx < n) rowptr[idx] = o.x;
        if (idx + 1 < n) rowptr[idx + 1] = o.y;
        if (idx + 2 < n) rowptr[idx + 2] = o.z;
    }
}

// atomic-free scatter using precomputed slots
__global__ __launch_bounds__(256) void scatter_kernel(const int* __restrict__ src,
                                                      const int* __restrict__ dst,
                                                      const int* __restrict__ epos, int E,
                                                      const int* __restrict__ rowptr,
                                                      int* __restrict__ csrsrc) {
    int e = blockIdx.x * 256 + threadIdx.x;
    if (e < E) csrsrc[rowptr[dst[e]] + epos[e]] = src[e];
}

// ---------------- dinv + prescale -> fp16 features ----------------

__global__ __launch_bounds__(256) void dinv_prescale_kernel(const float* __restrict__ x,
                                                            const int* __restrict__ deg,
                                                            float* __restrict__ dinv,
                                                            __half2* __restrict__ xs16, int n) {
    int node = blockIdx.x * 4 + (threadIdx.x >> 6);
    int lane = threadIdx.x & 63;
    if (node >= n) return;
    float di = rsqrtf((float)(deg[node] + 1));
    if (lane == 0) dinv[node] = di;
    float2 v = *(const float2*)(x + (size_t)node * 128 + (lane << 1));
    xs16[(size_t)node * 64 + lane] = __floats2half2_rn(di * v.x, di * v.y);
}

// ---------------- W transpose + bf16 split ----------------

__global__ __launch_bounds__(256) void wconvert_kernel(const float* __restrict__ W1,
                                                       const float* __restrict__ W2,
                                                       unsigned short* __restrict__ w1h,
                                                       unsigned short* __restrict__ w1l,
                                                       unsigned short* __restrict__ w2h,
                                                       unsigned short* __restrict__ w2l) {
    int i = blockIdx.x * 256 + threadIdx.x;
    if (i < 128 * 128) {
        int nn = i >> 7, k = i & 127;
        float v = W1[k * 128 + nn];
        unsigned short h = f2bf(v);
        w1h[i] = h;
        w1l[i] = f2bf(v - bf2f(h));
    } else if (i < 128 * 128 + 256 * 128) {
        int j = i - 128 * 128;
        int nn = j >> 7, k = j & 127;
        float v = W2[k * 256 + nn];
        unsigned short h = f2bf(v);
        w2h[j] = h;
        w2l[j] = f2bf(v - bf2f(h));
    }
}

// ---------------- aggregation: fp16 gather, fp32 accum, bf16 hi/lo out ----------------
// 16 lanes per node, 16B (8 halves) per lane; edge loop unrolled x4 for MLP.

__global__ __launch_bounds__(256) void aggregate_kernel(const unsigned short* __restrict__ X16,
                                                        const float* __restrict__ dinv,
                                                        const int* __restrict__ rowptr,
                                                        const int* __restrict__ deg,
                                                        const int* __restrict__ csrsrc,
                                                        unsigned short* __restrict__ outH,
                                                        unsigned short* __restrict__ outL, int n) {
    int node = blockIdx.x * 16 + (threadIdx.x >> 4);
    int sl = threadIdx.x & 15;
    if (node >= n) return;
    const uint4* Xv = (const uint4*)X16;  // row = 16 uint4 (128 halves)
    float acc[8] = {0.f, 0.f, 0.f, 0.f, 0.f, 0.f, 0.f, 0.f};
    addh8(acc, Xv[(size_t)node * 16 + sl]);  // self (prescaled)
    int e0 = rowptr[node];
    int e1 = e0 + deg[node];
    int e = e0;
    for (; e + 4 <= e1; e += 4) {
        int s0 = csrsrc[e], s1 = csrsrc[e + 1], s2 = csrsrc[e + 2], s3 = csrsrc[e + 3];
        uint4 v0 = Xv[(size_t)s0 * 16 + sl];
        uint4 v1 = Xv[(size_t)s1 * 16 + sl];
        uint4 v2 = Xv[(size_t)s2 * 16 + sl];
        uint4 v3 = Xv[(size_t)s3 * 16 + sl];
        addh8(acc, v0); addh8(acc, v1); addh8(acc, v2); addh8(acc, v3);
    }
    for (; e < e1; ++e) {
        uint4 v = Xv[(size_t)csrsrc[e] * 16 + sl];
        addh8(acc, v);
    }
    float di = dinv[node];
    unsigned short h[8], l[8];
#pragma unroll
    for (int j = 0; j < 8; ++j) {
        float f = di * acc[j];
        h[j] = f2bf(f);
        l[j] = f2bf(f - bf2f(h[j]));
    }
    uint4 hv, lv;
    hv.x = (unsigned)h[0] | ((unsigned)h[1] << 16);
    hv.y = (unsigned)h[2] | ((unsigned)h[3] << 16);
    hv.z = (unsigned)h[4] | ((unsigned)h[5] << 16);
    hv.w = (unsigned)h[6] | ((unsigned)h[7] << 16);
    lv.x = (unsigned)l[0] | ((unsigned)l[1] << 16);
    lv.y = (unsigned)l[2] | ((unsigned)l[3] << 16);
    lv.z = (unsigned)l[4] | ((unsigned)l[5] << 16);
    lv.w = (unsigned)l[6] | ((unsigned)l[7] << 16);
    *(uint4*)(outH + (size_t)node * 128 + sl * 8) = hv;
    *(uint4*)(outL + (size_t)node * 128 + sl * 8) = lv;
}

// ---------------- split-bf16 MFMA GEMM ----------------
// OUT_F16: C is written as fp16 (feeds next aggregate); else fp32.

template <int N, bool SCALE_DINV, bool DO_LOGITS, bool OUT_F16>
__global__ __launch_bounds__(256, 2) void gemm_mfma(const unsigned short* __restrict__ Ah,
                                                    const unsigned short* __restrict__ Al,
                                                    const unsigned short* __restrict__ Bth,
                                                    const unsigned short* __restrict__ Btl,
                                                    const float* __restrict__ bias,
                                                    void* __restrict__ Cout, int M,
                                                    const float* __restrict__ dinv,
                                                    const float* __restrict__ Wa,
                                                    float* __restrict__ logits) {
    __shared__ unsigned short AsH[128 * 64];
    __shared__ unsigned short AsL[128 * 64];
    __shared__ unsigned short BsH[128 * 64];
    __shared__ unsigned short BsL[128 * 64];

    const int t = threadIdx.x;
    const int lane = t & 63;
    const int wave = t >> 6;
    const int wrow = wave >> 1;
    const int wcol = wave & 1;
    const int lq = lane >> 4;
    const int lm = lane & 15;
    const int row0 = blockIdx.x * 128;
    const int col0 = blockIdx.y * 128;

    f32x4 acc[4][4] = {};
    float lacc[4][4] = {};

    for (int kc = 0; kc < 2; ++kc) {
        __syncthreads();
#pragma unroll
        for (int i = 0; i < 4; ++i) {
            int idx = t + i * 256;
            int r = idx >> 3;
            int g = idx & 7;
            int gr = row0 + r;
            uint4 vh = make_uint4(0, 0, 0, 0), vl = make_uint4(0, 0, 0, 0);
            if (gr < M) {
                const size_t go = (size_t)gr * 128 + kc * 64 + g * 8;
                vh = *(const uint4*)(Ah + go);
                vl = *(const uint4*)(Al + go);
            }
            int sg = g ^ (r & 7);
            *(uint4*)(AsH + r * 64 + sg * 8) = vh;
            *(uint4*)(AsL + r * 64 + sg * 8) = vl;
        }
#pragma unroll
        for (int i = 0; i < 4; ++i) {
            int idx = t + i * 256;
            int nn = idx >> 3;
            int g = idx & 7;
            const size_t go = (size_t)(col0 + nn) * 128 + kc * 64 + g * 8;
            int sg = g ^ (nn & 7);
            *(uint4*)(BsH + nn * 64 + sg * 8) = *(const uint4*)(Bth + go);
            *(uint4*)(BsL + nn * 64 + sg * 8) = *(const uint4*)(Btl + go);
        }
        __syncthreads();

#pragma unroll
        for (int ks = 0; ks < 2; ++ks) {
            bf16x8 ah[4], al[4], bh[4], bl[4];
            int gbase = ks * 4 + lq;
#pragma unroll
            for (int rt = 0; rt < 4; ++rt) {
                int ra = wrow * 64 + rt * 16 + lm;
                int off = ra * 64 + (gbase ^ (ra & 7)) * 8;
                ah[rt] = *(const bf16x8*)(AsH + off);
                al[rt] = *(const bf16x8*)(AsL + off);
            }
#pragma unroll
            for (int ct = 0; ct < 4; ++ct) {
                int nb = wcol * 64 + ct * 16 + lm;
                int off = nb * 64 + (gbase ^ (nb & 7)) * 8;
                bh[ct] = *(const bf16x8*)(BsH + off);
                bl[ct] = *(const bf16x8*)(BsL + off);
            }
#pragma unroll
            for (int rt = 0; rt < 4; ++rt)
#pragma unroll
                for (int ct = 0; ct < 4; ++ct) {
                    acc[rt][ct] = __builtin_amdgcn_mfma_f32_16x16x32_bf16(ah[rt], bh[ct], acc[rt][ct], 0, 0, 0);
                    acc[rt][ct] = __builtin_amdgcn_mfma_f32_16x16x32_bf16(al[rt], bh[ct], acc[rt][ct], 0, 0, 0);
                    acc[rt][ct] = __builtin_amdgcn_mfma_f32_16x16x32_bf16(ah[rt], bl[ct], acc[rt][ct], 0, 0, 0);
                }
        }
    }

#pragma unroll
    for (int ct = 0; ct < 4; ++ct) {
        int col = col0 + wcol * 64 + ct * 16 + lm;
        float bc = bias[col];
        float wac = DO_LOGITS ? Wa[col] : 0.f;
#pragma unroll
        for (int rt = 0; rt < 4; ++rt) {
            int rowb = row0 + wrow * 64 + rt * 16 + lq * 4;
#pragma unroll
            for (int reg = 0; reg < 4; ++reg) {
                int gr = rowb + reg;
                if (gr < M) {
                    float o = fmaxf(acc[rt][ct][reg] + bc, 0.f);
                    if (SCALE_DINV) o *= dinv[gr];
                    if (OUT_F16) ((__half*)Cout)[(size_t)gr * N + col] = __float2half(o);
                    else ((float*)Cout)[(size_t)gr * N + col] = o;
                    if (DO_LOGITS) lacc[rt][reg] += o * wac;
                }
            }
        }
    }

    if (DO_LOGITS) {
#pragma unroll
        for (int rt = 0; rt < 4; ++rt)
#pragma unroll
            for (int reg = 0; reg < 4; ++reg) {
                float s = lacc[rt][reg];
                s += __shfl_xor(s, 1);
                s += __shfl_xor(s, 2);
                s += __shfl_xor(s, 4);
                s += __shfl_xor(s, 8);
                int gr = row0 + wrow * 64 + rt * 16 + lq * 4 + reg;
                if (lm == 0 && gr < M) atomicAdd(&logits[gr], s);
            }
    }
}

// ---------------- attention pooling ----------------

__global__ __launch_bounds__(256) void maxsum_kernel(const float* __restrict__ logits, int n,
                                                     float2* __restrict__ part) {
    float m = -INFINITY, s = 0.f;
    for (int i = blockIdx.x * 256 + threadIdx.x; i < n; i += gridDim.x * 256) {
        float v = logits[i];
        if (v > m) { s = s * expf(m - v) + 1.f; m = v; }
        else s += expf(v - m);
    }
    __shared__ float sm[256], ss[256];
    sm[threadIdx.x] = m; ss[threadIdx.x] = s;
    __syncthreads();
    for (int off = 128; off > 0; off >>= 1) {
        if (threadIdx.x < off) {
            float m1 = sm[threadIdx.x], s1 = ss[threadIdx.x];
            float m2 = sm[threadIdx.x + off], s2 = ss[threadIdx.x + off];
            float M = fmaxf(m1, m2);
            sm[threadIdx.x] = M;
            ss[threadIdx.x] = s1 * expf(m1 - M) + s2 * expf(m2 - M);
        }
        __syncthreads();
    }
    if (threadIdx.x == 0) part[blockIdx.x] = make_float2(sm[0], ss[0]);
}

__global__ __launch_bounds__(64) void merge_kernel(const float2* __restrict__ part,
                                                   float* __restrict__ gms) {
    __shared__ float sm[64], ss[64];
    float2 p = part[threadIdx.x];
    sm[threadIdx.x] = p.x; ss[threadIdx.x] = p.y;
    __syncthreads();
    for (int off = 32; off > 0; off >>= 1) {
        if (threadIdx.x < off) {
            float m1 = sm[threadIdx.x], s1 = ss[threadIdx.x];
            float m2 = sm[threadIdx.x + off], s2 = ss[threadIdx.x + off];
            float M = fmaxf(m1, m2);
            sm[threadIdx.x] = M;
            ss[threadIdx.x] = s1 * expf(m1 - M) + s2 * expf(m2 - M);
        }
        __syncthreads();
    }
    if (threadIdx.x == 0) { gms[0] = sm[0]; gms[1] = ss[0]; }
}

__global__ __launch_bounds__(256) void weighted_sum_kernel(const float* __restrict__ emb,
                                                           const float* __restrict__ logits,
                                                           const float* __restrict__ gms,
                                                           float* __restrict__ outTail, int n) {
    float g = gms[0];
    int c = threadIdx.x;
    float acc = 0.f;
    for (int i = blockIdx.x; i < n; i += gridDim.x) {
        float w = expf(logits[i] - g);
        acc += w * emb[(size_t)i * 256 + c];
    }
    atomicAdd(&outTail[c], acc);
}

__global__ __launch_bounds__(256) void normalize_kernel(float* __restrict__ outTail,
                                                        const float* __restrict__ gms) {
    outTail[threadIdx.x] = outTail[threadIdx.x] / gms[1];
}

// ---------------- launch ----------------

extern "C" void kernel_launch(void* const* d_in, const int* in_sizes, int n_in,
                              void* d_out, int out_size, void* d_ws, size_t ws_size,
                              hipStream_t stream) {
    const float* x  = (const float*)d_in[0];
    const int* ei   = (const int*)d_in[1];
    const float* W1 = (const float*)d_in[2];
    const float* b1 = (const float*)d_in[3];
    const float* W2 = (const float*)d_in[4];
    const float* b2 = (const float*)d_in[5];
    const float* Wa = (const float*)d_in[6];
    float* out = (float*)d_out;

    const int n = in_sizes[0] / 128;  // 50000
    const int E = in_sizes[1] / 2;    // 800000
    const int* srcA = ei;
    const int* dstA = ei + E;
    const int nb = (n + 1023) / 1024;

    // workspace layout
    unsigned short* xs16 = (unsigned short*)d_ws;         // n*128 fp16 (prescaled x, then h1)
    unsigned short* aggH = xs16 + (size_t)n * 128;        // n*128 bf16
    unsigned short* aggL = aggH + (size_t)n * 128;
    unsigned short* w1h  = aggL + (size_t)n * 128;        // 128*128
    unsigned short* w1l  = w1h + 128 * 128;
    unsigned short* w2h  = w1l + 128 * 128;               // 256*128
    unsigned short* w2l  = w2h + 256 * 128;
    float* dinv   = (float*)(w2l + 256 * 128);            // n
    float* logits = dinv + n;                             // n
    float2* part  = (float2*)(logits + n);                // 64
    float* gms    = (float*)(part + 64);                  // 2
    int* deg      = (int*)(gms + 2);                      // n
    int* rowptr   = deg + n;                              // n+1
    int* partials = rowptr + n + 1;                       // 64
    int* poff     = partials + 64;                        // 64
    int* epos     = poff + 64;                            // E
    int* csrsrc   = epos + E;                             // E

    hipMemsetAsync(deg, 0, sizeof(int) * (size_t)n, stream);
    hipMemsetAsync(logits, 0, sizeof(float) * (size_t)n, stream);
    hipMemsetAsync(out + (size_t)n * 256, 0, sizeof(float) * 256, stream);

    count_deg_kernel<<<(E + 255) / 256, 256, 0, stream>>>(dstA, E, deg, epos);
    scan_partial_kernel<<<nb, 256, 0, stream>>>(deg, n, partials);
    scan_offsets_kernel<<<1, 64, 0, stream>>>(partials, nb, poff, rowptr, n);
    scan_final_kernel<<<nb, 256, 0, stream>>>(deg, n, poff, rowptr);
    scatter_kernel<<<(E + 255) / 256, 256, 0, stream>>>(srcA, dstA, epos, E, rowptr, csrsrc);
    dinv_prescale_kernel<<<(n + 3) / 4, 256, 0, stream>>>(x, deg, dinv, (__half2*)xs16, n);
    wconvert_kernel<<<(128 * 128 + 256 * 128 + 255) / 256, 256, 0, stream>>>(W1, W2, w1h, w1l, w2h, w2l);

    int aggBlocks = (n + 15) / 16;
    int gemmRows = (n + 127) / 128;

    // layer 1: fp16 gather-aggregate -> bf16 planes -> GEMM -> fp16 h1 (into xs16)
    aggregate_kernel<<<aggBlocks, 256, 0, stream>>>(xs16, dinv, rowptr, deg, csrsrc, aggH, aggL, n);
    gemm_mfma<128, true, false, true><<<dim3(gemmRows, 1), 256, 0, stream>>>(
        aggH, aggL, w1h, w1l, b1, xs16, n, dinv, nullptr, nullptr);
    // layer 2 (+fused logits)
    aggregate_kernel<<<aggBlocks, 256, 0, stream>>>(xs16, dinv, rowptr, deg, csrsrc, aggH, aggL, n);
    gemm_mfma<256, false, true, false><<<dim3(gemmRows, 2), 256, 0, stream>>>(
        aggH, aggL, w2h, w2l, b2, out, n, nullptr, Wa, logits);

    maxsum_kernel<<<64, 256, 0, stream>>>(logits, n, part);
    merge_kernel<<<1, 64, 0, stream>>>(part, gms);
    weighted_sum_kernel<<<512, 256, 0, stream>>>(out, logits, gms, out + (size_t)n * 256, n);
    normalize_kernel<<<1, 256, 0, stream>>>(out + (size_t)n * 256, gms);
}

// Round 6
// 311.361 us; speedup vs baseline: 1.9340x; 1.0752x over previous
//
#include <hip/hip_runtime.h>
#include <hip/hip_fp16.h>
#include <math.h>

typedef __attribute__((ext_vector_type(8))) short bf16x8;
typedef __attribute__((ext_vector_type(4))) float f32x4;

static __device__ __forceinline__ unsigned short f2bf(float x) {
    unsigned u = __float_as_uint(x);
    unsigned r = (u + 0x7FFF + ((u >> 16) & 1)) >> 16;
    return (unsigned short)r;
}
static __device__ __forceinline__ float bf2f(unsigned short h) {
    return __uint_as_float(((unsigned)h) << 16);
}
static __device__ __forceinline__ void addh8(float a[8], uint4 v) {
    float2 f;
    f = __half22float2(*(const __half2*)&v.x); a[0] += f.x; a[1] += f.y;
    f = __half22float2(*(const __half2*)&v.y); a[2] += f.x; a[3] += f.y;
    f = __half22float2(*(const __half2*)&v.z); a[4] += f.x; a[5] += f.y;
    f = __half22float2(*(const __half2*)&v.w); a[6] += f.x; a[7] += f.y;
}

// ---------------- CSR build ----------------

__global__ __launch_bounds__(256) void count_deg_kernel(const int* __restrict__ dst, int E,
                                                        int* __restrict__ deg,
                                                        int* __restrict__ epos) {
    int e = blockIdx.x * 256 + threadIdx.x;
    if (e < E) epos[e] = atomicAdd(&deg[dst[e]], 1);
}

__global__ __launch_bounds__(256) void scan_partial_kernel(const int* __restrict__ deg, int n,
                                                           int* __restrict__ partials) {
    int idx = blockIdx.x * 1024 + threadIdx.x * 4;
    int4 v = make_int4(0, 0, 0, 0);
    if (idx + 3 < n) v = *(const int4*)(deg + idx);
    else {
        if (idx < n) v.x = deg[idx];
        if (idx + 1 < n) v.y = deg[idx + 1];
        if (idx + 2 < n) v.z = deg[idx + 2];
    }
    int s = v.x + v.y + v.z + v.w;
    for (int off = 1; off < 64; off <<= 1) s += __shfl_xor(s, off);
    __shared__ int sm[4];
    int wave = threadIdx.x >> 6;
    if ((threadIdx.x & 63) == 0) sm[wave] = s;
    __syncthreads();
    if (threadIdx.x == 0) partials[blockIdx.x] = sm[0] + sm[1] + sm[2] + sm[3];
}

__global__ __launch_bounds__(64) void scan_offsets_kernel(const int* __restrict__ partials, int nb,
                                                          int* __restrict__ poff,
                                                          int* __restrict__ rowptr, int n) {
    int t = threadIdx.x;
    int v = (t < nb) ? partials[t] : 0;
    int s = v;
    for (int off = 1; off < 64; off <<= 1) {
        int u = __shfl_up(s, off);
        if (t >= off) s += u;
    }
    poff[t] = s - v;
    if (t == 63) rowptr[n] = s;
}

__global__ __launch_bounds__(256) void scan_final_kernel(const int* __restrict__ deg, int n,
                                                         const int* __restrict__ poff,
                                                         int* __restrict__ rowptr) {
    int idx = blockIdx.x * 1024 + threadIdx.x * 4;
    int4 v = make_int4(0, 0, 0, 0);
    if (idx + 3 < n) v = *(const int4*)(deg + idx);
    else {
        if (idx < n) v.x = deg[idx];
        if (idx + 1 < n) v.y = deg[idx + 1];
        if (idx + 2 < n) v.z = deg[idx + 2];
    }
    int tsum = v.x + v.y + v.z + v.w;
    int lane = threadIdx.x & 63, wave = threadIdx.x >> 6;
    int s = tsum;
    for (int off = 1; off < 64; off <<= 1) {
        int u = __shfl_up(s, off);
        if (lane >= off) s += u;
    }
    __shared__ int wsum[4];
    if (lane == 63) wsum[wave] = s;
    __syncthreads();
    int base = poff[blockIdx.x];
    for (int w = 0; w < wave; ++w) base += wsum[w];
    int e0 = base + s - tsum;
    int4 o;
    o.x = e0; o.y = e0 + v.x; o.z = o.y + v.y; o.w = o.z + v.z;
    if (idx + 3 < n) *(int4*)(rowptr + idx) = o;
    else {
        if (idx < n) rowptr[idx] = o.x;
        if (idx + 1 < n) rowptr[idx + 1] = o.y;
        if (idx + 2 < n) rowptr[idx + 2] = o.z;
    }
}

__global__ __launch_bounds__(256) void scatter_kernel(const int* __restrict__ src,
                                                      const int* __restrict__ dst,
                                                      const int* __restrict__ epos, int E,
                                                      const int* __restrict__ rowptr,
                                                      int* __restrict__ csrsrc) {
    int e = blockIdx.x * 256 + threadIdx.x;
    if (e < E) csrsrc[rowptr[dst[e]] + epos[e]] = src[e];
}

// ---------------- dinv + prescale -> fp16 features ----------------

__global__ __launch_bounds__(256) void dinv_prescale_kernel(const float* __restrict__ x,
                                                            const int* __restrict__ deg,
                                                            float* __restrict__ dinv,
                                                            __half2* __restrict__ xs16, int n) {
    int node = blockIdx.x * 4 + (threadIdx.x >> 6);
    int lane = threadIdx.x & 63;
    if (node >= n) return;
    float di = rsqrtf((float)(deg[node] + 1));
    if (lane == 0) dinv[node] = di;
    float2 v = *(const float2*)(x + (size_t)node * 128 + (lane << 1));
    xs16[(size_t)node * 64 + lane] = __floats2half2_rn(di * v.x, di * v.y);
}

// ---------------- W transpose + bf16 split ----------------

__global__ __launch_bounds__(256) void wconvert_kernel(const float* __restrict__ W1,
                                                       const float* __restrict__ W2,
                                                       unsigned short* __restrict__ w1h,
                                                       unsigned short* __restrict__ w1l,
                                                       unsigned short* __restrict__ w2h,
                                                       unsigned short* __restrict__ w2l) {
    int i = blockIdx.x * 256 + threadIdx.x;
    if (i < 128 * 128) {
        int nn = i >> 7, k = i & 127;
        float v = W1[k * 128 + nn];
        unsigned short h = f2bf(v);
        w1h[i] = h;
        w1l[i] = f2bf(v - bf2f(h));
    } else if (i < 128 * 128 + 256 * 128) {
        int j = i - 128 * 128;
        int nn = j >> 7, k = j & 127;
        float v = W2[k * 256 + nn];
        unsigned short h = f2bf(v);
        w2h[j] = h;
        w2l[j] = f2bf(v - bf2f(h));
    }
}

// ---------------- aggregation: fp16 gather, fp32 accum, bf16 hi/lo out ----------------

__global__ __launch_bounds__(256) void aggregate_kernel(const unsigned short* __restrict__ X16,
                                                        const float* __restrict__ dinv,
                                                        const int* __restrict__ rowptr,
                                                        const int* __restrict__ deg,
                                                        const int* __restrict__ csrsrc,
                                                        unsigned short* __restrict__ outH,
                                                        unsigned short* __restrict__ outL, int n) {
    int node = blockIdx.x * 16 + (threadIdx.x >> 4);
    int sl = threadIdx.x & 15;
    if (node >= n) return;
    const uint4* Xv = (const uint4*)X16;
    float acc[8] = {0.f, 0.f, 0.f, 0.f, 0.f, 0.f, 0.f, 0.f};
    addh8(acc, Xv[(size_t)node * 16 + sl]);
    int e0 = rowptr[node];
    int e1 = e0 + deg[node];
    int e = e0;
    for (; e + 4 <= e1; e += 4) {
        int s0 = csrsrc[e], s1 = csrsrc[e + 1], s2 = csrsrc[e + 2], s3 = csrsrc[e + 3];
        uint4 v0 = Xv[(size_t)s0 * 16 + sl];
        uint4 v1 = Xv[(size_t)s1 * 16 + sl];
        uint4 v2 = Xv[(size_t)s2 * 16 + sl];
        uint4 v3 = Xv[(size_t)s3 * 16 + sl];
        addh8(acc, v0); addh8(acc, v1); addh8(acc, v2); addh8(acc, v3);
    }
    for (; e < e1; ++e) {
        uint4 v = Xv[(size_t)csrsrc[e] * 16 + sl];
        addh8(acc, v);
    }
    float di = dinv[node];
    unsigned short h[8], l[8];
#pragma unroll
    for (int j = 0; j < 8; ++j) {
        float f = di * acc[j];
        h[j] = f2bf(f);
        l[j] = f2bf(f - bf2f(h[j]));
    }
    uint4 hv, lv;
    hv.x = (unsigned)h[0] | ((unsigned)h[1] << 16);
    hv.y = (unsigned)h[2] | ((unsigned)h[3] << 16);
    hv.z = (unsigned)h[4] | ((unsigned)h[5] << 16);
    hv.w = (unsigned)h[6] | ((unsigned)h[7] << 16);
    lv.x = (unsigned)l[0] | ((unsigned)l[1] << 16);
    lv.y = (unsigned)l[2] | ((unsigned)l[3] << 16);
    lv.z = (unsigned)l[4] | ((unsigned)l[5] << 16);
    lv.w = (unsigned)l[6] | ((unsigned)l[7] << 16);
    *(uint4*)(outH + (size_t)node * 128 + sl * 8) = hv;
    *(uint4*)(outL + (size_t)node * 128 + sl * 8) = lv;
}

// ---------------- split-bf16 MFMA GEMM ----------------

template <int N, bool SCALE_DINV, bool DO_LOGITS, bool OUT_F16>
__global__ __launch_bounds__(256, 2) void gemm_mfma(const unsigned short* __restrict__ Ah,
                                                    const unsigned short* __restrict__ Al,
                                                    const unsigned short* __restrict__ Bth,
                                                    const unsigned short* __restrict__ Btl,
                                                    const float* __restrict__ bias,
                                                    void* __restrict__ Cout, int M,
                                                    const float* __restrict__ dinv,
                                                    const float* __restrict__ Wa,
                                                    float* __restrict__ logits) {
    __shared__ unsigned short AsH[128 * 64];
    __shared__ unsigned short AsL[128 * 64];
    __shared__ unsigned short BsH[128 * 64];
    __shared__ unsigned short BsL[128 * 64];

    const int t = threadIdx.x;
    const int lane = t & 63;
    const int wave = t >> 6;
    const int wrow = wave >> 1;
    const int wcol = wave & 1;
    const int lq = lane >> 4;
    const int lm = lane & 15;
    const int row0 = blockIdx.x * 128;
    const int col0 = blockIdx.y * 128;

    f32x4 acc[4][4] = {};
    float lacc[4][4] = {};

    for (int kc = 0; kc < 2; ++kc) {
        __syncthreads();
#pragma unroll
        for (int i = 0; i < 4; ++i) {
            int idx = t + i * 256;
            int r = idx >> 3;
            int g = idx & 7;
            int gr = row0 + r;
            uint4 vh = make_uint4(0, 0, 0, 0), vl = make_uint4(0, 0, 0, 0);
            if (gr < M) {
                const size_t go = (size_t)gr * 128 + kc * 64 + g * 8;
                vh = *(const uint4*)(Ah + go);
                vl = *(const uint4*)(Al + go);
            }
            int sg = g ^ (r & 7);
            *(uint4*)(AsH + r * 64 + sg * 8) = vh;
            *(uint4*)(AsL + r * 64 + sg * 8) = vl;
        }
#pragma unroll
        for (int i = 0; i < 4; ++i) {
            int idx = t + i * 256;
            int nn = idx >> 3;
            int g = idx & 7;
            const size_t go = (size_t)(col0 + nn) * 128 + kc * 64 + g * 8;
            int sg = g ^ (nn & 7);
            *(uint4*)(BsH + nn * 64 + sg * 8) = *(const uint4*)(Bth + go);
            *(uint4*)(BsL + nn * 64 + sg * 8) = *(const uint4*)(Btl + go);
        }
        __syncthreads();

#pragma unroll
        for (int ks = 0; ks < 2; ++ks) {
            bf16x8 ah[4], al[4], bh[4], bl[4];
            int gbase = ks * 4 + lq;
#pragma unroll
            for (int rt = 0; rt < 4; ++rt) {
                int ra = wrow * 64 + rt * 16 + lm;
                int off = ra * 64 + (gbase ^ (ra & 7)) * 8;
                ah[rt] = *(const bf16x8*)(AsH + off);
                al[rt] = *(const bf16x8*)(AsL + off);
            }
#pragma unroll
            for (int ct = 0; ct < 4; ++ct) {
                int nb = wcol * 64 + ct * 16 + lm;
                int off = nb * 64 + (gbase ^ (nb & 7)) * 8;
                bh[ct] = *(const bf16x8*)(BsH + off);
                bl[ct] = *(const bf16x8*)(BsL + off);
            }
#pragma unroll
            for (int rt = 0; rt < 4; ++rt)
#pragma unroll
                for (int ct = 0; ct < 4; ++ct) {
                    acc[rt][ct] = __builtin_amdgcn_mfma_f32_16x16x32_bf16(ah[rt], bh[ct], acc[rt][ct], 0, 0, 0);
                    acc[rt][ct] = __builtin_amdgcn_mfma_f32_16x16x32_bf16(al[rt], bh[ct], acc[rt][ct], 0, 0, 0);
                    acc[rt][ct] = __builtin_amdgcn_mfma_f32_16x16x32_bf16(ah[rt], bl[ct], acc[rt][ct], 0, 0, 0);
                }
        }
    }

#pragma unroll
    for (int ct = 0; ct < 4; ++ct) {
        int col = col0 + wcol * 64 + ct * 16 + lm;
        float bc = bias[col];
        float wac = DO_LOGITS ? Wa[col] : 0.f;
#pragma unroll
        for (int rt = 0; rt < 4; ++rt) {
            int rowb = row0 + wrow * 64 + rt * 16 + lq * 4;
#pragma unroll
            for (int reg = 0; reg < 4; ++reg) {
                int gr = rowb + reg;
                if (gr < M) {
                    float o = fmaxf(acc[rt][ct][reg] + bc, 0.f);
                    if (SCALE_DINV) o *= dinv[gr];
                    if (OUT_F16) ((__half*)Cout)[(size_t)gr * N + col] = __float2half(o);
                    else ((float*)Cout)[(size_t)gr * N + col] = o;
                    if (DO_LOGITS) lacc[rt][reg] += o * wac;
                }
            }
        }
    }

    if (DO_LOGITS) {
#pragma unroll
        for (int rt = 0; rt < 4; ++rt)
#pragma unroll
            for (int reg = 0; reg < 4; ++reg) {
                float s = lacc[rt][reg];
                s += __shfl_xor(s, 1);
                s += __shfl_xor(s, 2);
                s += __shfl_xor(s, 4);
                s += __shfl_xor(s, 8);
                int gr = row0 + wrow * 64 + rt * 16 + lq * 4 + reg;
                if (lm == 0 && gr < M) atomicAdd(&logits[gr], s);
            }
    }
}

// ---------------- attention pooling ----------------

__global__ __launch_bounds__(256) void maxsum_kernel(const float* __restrict__ logits, int n,
                                                     float2* __restrict__ part) {
    float m = -INFINITY, s = 0.f;
    for (int i = blockIdx.x * 256 + threadIdx.x; i < n; i += gridDim.x * 256) {
        float v = logits[i];
        if (v > m) { s = s * expf(m - v) + 1.f; m = v; }
        else s += expf(v - m);
    }
    __shared__ float sm[256], ss[256];
    sm[threadIdx.x] = m; ss[threadIdx.x] = s;
    __syncthreads();
    for (int off = 128; off > 0; off >>= 1) {
        if (threadIdx.x < off) {
            float m1 = sm[threadIdx.x], s1 = ss[threadIdx.x];
            float m2 = sm[threadIdx.x + off], s2 = ss[threadIdx.x + off];
            float M = fmaxf(m1, m2);
            sm[threadIdx.x] = M;
            ss[threadIdx.x] = s1 * expf(m1 - M) + s2 * expf(m2 - M);
        }
        __syncthreads();
    }
    if (threadIdx.x == 0) part[blockIdx.x] = make_float2(sm[0], ss[0]);
}

__global__ __launch_bounds__(64) void merge_kernel(const float2* __restrict__ part,
                                                   float* __restrict__ gms) {
    __shared__ float sm[64], ss[64];
    float2 p = part[threadIdx.x];
    sm[threadIdx.x] = p.x; ss[threadIdx.x] = p.y;
    __syncthreads();
    for (int off = 32; off > 0; off >>= 1) {
        if (threadIdx.x < off) {
            float m1 = sm[threadIdx.x], s1 = ss[threadIdx.x];
            float m2 = sm[threadIdx.x + off], s2 = ss[threadIdx.x + off];
            float M = fmaxf(m1, m2);
            sm[threadIdx.x] = M;
            ss[threadIdx.x] = s1 * expf(m1 - M) + s2 * expf(m2 - M);
        }
        __syncthreads();
    }
    if (threadIdx.x == 0) { gms[0] = sm[0]; gms[1] = ss[0]; }
}

// wave-per-row weighted sum; per-block partials (no global atomics).
// block = 4 waves; wave handles rows blockIdx*4+wave, stride gridDim*4; lane covers 4 cols.
__global__ __launch_bounds__(256) void weighted_sum_kernel(const float* __restrict__ emb,
                                                           const float* __restrict__ logits,
                                                           const float* __restrict__ gms,
                                                           float* __restrict__ gpart, int n) {
    float g = gms[0];
    int wave = threadIdx.x >> 6;
    int lane = threadIdx.x & 63;
    int stride = gridDim.x * 4;
    float4 acc = make_float4(0.f, 0.f, 0.f, 0.f);
#pragma unroll 2
    for (int r = blockIdx.x * 4 + wave; r < n; r += stride) {
        float w = expf(logits[r] - g);
        float4 v = *(const float4*)(emb + (size_t)r * 256 + (lane << 2));
        acc.x += w * v.x; acc.y += w * v.y; acc.z += w * v.z; acc.w += w * v.w;
    }
    __shared__ float4 sm[256];
    sm[threadIdx.x] = acc;
    __syncthreads();
    if (wave == 0) {
        float4 a = sm[lane], b = sm[64 + lane], c = sm[128 + lane], d = sm[192 + lane];
        float4 s;
        s.x = (a.x + b.x) + (c.x + d.x);
        s.y = (a.y + b.y) + (c.y + d.y);
        s.z = (a.z + b.z) + (c.z + d.z);
        s.w = (a.w + b.w) + (c.w + d.w);
        *(float4*)(gpart + (size_t)blockIdx.x * 256 + (lane << 2)) = s;
    }
}

// reduce gpart[nb][256] -> outTail (pre-zeroed) via 32 blocks + atomics
__global__ __launch_bounds__(256) void reduce_gpart_kernel(const float* __restrict__ gpart,
                                                           float* __restrict__ outTail, int nb) {
    int rows = nb / gridDim.x;
    int r0 = blockIdx.x * rows;
    float s = 0.f;
    for (int r = r0; r < r0 + rows; ++r) s += gpart[(size_t)r * 256 + threadIdx.x];
    atomicAdd(&outTail[threadIdx.x], s);
}

__global__ __launch_bounds__(256) void normalize_kernel(float* __restrict__ outTail,
                                                        const float* __restrict__ gms) {
    outTail[threadIdx.x] = outTail[threadIdx.x] / gms[1];
}

// ---------------- launch ----------------

extern "C" void kernel_launch(void* const* d_in, const int* in_sizes, int n_in,
                              void* d_out, int out_size, void* d_ws, size_t ws_size,
                              hipStream_t stream) {
    const float* x  = (const float*)d_in[0];
    const int* ei   = (const int*)d_in[1];
    const float* W1 = (const float*)d_in[2];
    const float* b1 = (const float*)d_in[3];
    const float* W2 = (const float*)d_in[4];
    const float* b2 = (const float*)d_in[5];
    const float* Wa = (const float*)d_in[6];
    float* out = (float*)d_out;

    const int n = in_sizes[0] / 128;  // 50000
    const int E = in_sizes[1] / 2;    // 800000
    const int* srcA = ei;
    const int* dstA = ei + E;
    const int nb = (n + 1023) / 1024;
    const int WS_BLOCKS = 1024;       // weighted-sum grid (divisible by 32)

    // workspace layout
    unsigned short* xs16 = (unsigned short*)d_ws;         // n*128 fp16
    unsigned short* aggH = xs16 + (size_t)n * 128;        // n*128 bf16
    unsigned short* aggL = aggH + (size_t)n * 128;
    unsigned short* w1h  = aggL + (size_t)n * 128;        // 128*128
    unsigned short* w1l  = w1h + 128 * 128;
    unsigned short* w2h  = w1l + 128 * 128;               // 256*128
    unsigned short* w2l  = w2h + 256 * 128;
    float* dinv   = (float*)(w2l + 256 * 128);            // n
    float* logits = dinv + n;                             // n
    float2* part  = (float2*)(logits + n);                // 64
    float* gms    = (float*)(part + 64);                  // 2
    float* gpart  = gms + 2;                              // WS_BLOCKS*256
    int* deg      = (int*)(gpart + WS_BLOCKS * 256);      // n
    int* rowptr   = deg + n;                              // n+1
    int* partials = rowptr + n + 1;                       // 64
    int* poff     = partials + 64;                        // 64
    int* epos     = poff + 64;                            // E
    int* csrsrc   = epos + E;                             // E

    hipMemsetAsync(deg, 0, sizeof(int) * (size_t)n, stream);
    hipMemsetAsync(logits, 0, sizeof(float) * (size_t)n, stream);
    hipMemsetAsync(out + (size_t)n * 256, 0, sizeof(float) * 256, stream);

    count_deg_kernel<<<(E + 255) / 256, 256, 0, stream>>>(dstA, E, deg, epos);
    scan_partial_kernel<<<nb, 256, 0, stream>>>(deg, n, partials);
    scan_offsets_kernel<<<1, 64, 0, stream>>>(partials, nb, poff, rowptr, n);
    scan_final_kernel<<<nb, 256, 0, stream>>>(deg, n, poff, rowptr);
    scatter_kernel<<<(E + 255) / 256, 256, 0, stream>>>(srcA, dstA, epos, E, rowptr, csrsrc);
    dinv_prescale_kernel<<<(n + 3) / 4, 256, 0, stream>>>(x, deg, dinv, (__half2*)xs16, n);
    wconvert_kernel<<<(128 * 128 + 256 * 128 + 255) / 256, 256, 0, stream>>>(W1, W2, w1h, w1l, w2h, w2l);

    int aggBlocks = (n + 15) / 16;
    int gemmRows = (n + 127) / 128;

    aggregate_kernel<<<aggBlocks, 256, 0, stream>>>(xs16, dinv, rowptr, deg, csrsrc, aggH, aggL, n);
    gemm_mfma<128, true, false, true><<<dim3(gemmRows, 1), 256, 0, stream>>>(
        aggH, aggL, w1h, w1l, b1, xs16, n, dinv, nullptr, nullptr);
    aggregate_kernel<<<aggBlocks, 256, 0, stream>>>(xs16, dinv, rowptr, deg, csrsrc, aggH, aggL, n);
    gemm_mfma<256, false, true, false><<<dim3(gemmRows, 2), 256, 0, stream>>>(
        aggH, aggL, w2h, w2l, b2, out, n, nullptr, Wa, logits);

    maxsum_kernel<<<64, 256, 0, stream>>>(logits, n, part);
    merge_kernel<<<1, 64, 0, stream>>>(part, gms);
    weighted_sum_kernel<<<WS_BLOCKS, 256, 0, stream>>>(out, logits, gms, gpart, n);
    reduce_gpart_kernel<<<32, 256, 0, stream>>>(gpart, out + (size_t)n * 256, WS_BLOCKS);
    normalize_kernel<<<1, 256, 0, stream>>>(out + (size_t)n * 256, gms);
}